// Round 1
// baseline (704.424 us; speedup 1.0000x reference)
//
#include <hip/hip_runtime.h>
#include <math.h>

#define NEG_SLOPE 0.2f

// ---------------- CSR build ----------------

__global__ __launch_bounds__(256) void degree_hist(const int* __restrict__ dst,
                                                   int* __restrict__ deg, int E) {
    int e = blockIdx.x * blockDim.x + threadIdx.x;
    if (e < E) atomicAdd(&deg[dst[e]], 1);
}

__global__ __launch_bounds__(1024) void exclusive_scan(const int* __restrict__ in,
                                                       int* __restrict__ out, int n) {
    __shared__ int buf[1024];
    __shared__ int carry;
    if (threadIdx.x == 0) carry = 0;
    __syncthreads();
    for (int base = 0; base < n; base += 1024) {
        int i = base + (int)threadIdx.x;
        int v = (i < n) ? in[i] : 0;
        buf[threadIdx.x] = v;
        __syncthreads();
        for (int off = 1; off < 1024; off <<= 1) {
            int t = (threadIdx.x >= (unsigned)off) ? buf[threadIdx.x - off] : 0;
            __syncthreads();
            buf[threadIdx.x] += t;
            __syncthreads();
        }
        if (i < n) out[i] = carry + buf[threadIdx.x] - v;
        int total = buf[1023];
        __syncthreads();
        if (threadIdx.x == 0) carry += total;
        __syncthreads();
    }
    if (threadIdx.x == 0) out[n] = carry;
}

__global__ __launch_bounds__(256) void scatter_edges(const int* __restrict__ src,
                                                     const int* __restrict__ dst,
                                                     const int* __restrict__ row_start,
                                                     int* __restrict__ cursor,
                                                     int* __restrict__ csr_src, int E) {
    int e = blockIdx.x * blockDim.x + threadIdx.x;
    if (e >= E) return;
    int d = dst[e];
    int pos = atomicAdd(&cursor[d], 1);
    csr_src[row_start[d] + pos] = src[e];
}

// ---------------- GEMM: out[N,M] = x[N,K] @ W[K,M] ----------------

template <int K, int M>
__global__ __launch_bounds__(256) void gemm_feat(const float* __restrict__ x,
                                                 const float* __restrict__ W,
                                                 float* __restrict__ out, int N) {
    constexpr int NGRP = 256 / M;   // row groups processed in parallel
    constexpr int RPG  = 8;         // rows per group
    constexpr int ROWS = NGRP * RPG;
    __shared__ float sx[ROWS][K];
    const int tid = threadIdx.x;
    const int col = tid % M;
    const int grp = tid / M;
    for (int base = blockIdx.x * ROWS; base < N; base += gridDim.x * ROWS) {
        __syncthreads();
        for (int i = tid; i < ROWS * K; i += 256) {
            int r = i / K, c = i % K;
            int row = base + r;
            sx[r][c] = (row < N) ? x[(size_t)row * K + c] : 0.f;
        }
        __syncthreads();
        if (grp < NGRP) {
            float acc[RPG];
#pragma unroll
            for (int rr = 0; rr < RPG; ++rr) acc[rr] = 0.f;
            for (int k = 0; k < K; ++k) {
                float w = W[(size_t)k * M + col];
#pragma unroll
                for (int rr = 0; rr < RPG; ++rr) acc[rr] += sx[grp * RPG + rr][k] * w;
            }
#pragma unroll
            for (int rr = 0; rr < RPG; ++rr) {
                int row = base + grp * RPG + rr;
                if (row < N) out[(size_t)row * M + col] = acc[rr];
            }
        }
    }
}

// ---------------- attention scores el/er per (node, head) ----------------

template <int H, int D>
__global__ __launch_bounds__(256) void attn_scores(const float* __restrict__ feat,
                                                   const float* __restrict__ al,
                                                   const float* __restrict__ ar,
                                                   float* __restrict__ el,
                                                   float* __restrict__ er, int N) {
    int node = (blockIdx.x * blockDim.x + threadIdx.x) >> 6;
    int lane = threadIdx.x & 63;
    if (node >= N) return;
#pragma unroll
    for (int h = 0; h < H; ++h) {
        float v = 0.f, w = 0.f;
        if (lane < D) {
            float f = feat[(size_t)node * (H * D) + h * D + lane];
            v = f * al[h * D + lane];
            w = f * ar[h * D + lane];
        }
#pragma unroll
        for (int off = 32; off; off >>= 1) {
            v += __shfl_down(v, off);
            w += __shfl_down(w, off);
        }
        if (lane == 0) {
            el[(size_t)node * H + h] = v;
            er[(size_t)node * H + h] = w;
        }
    }
}

// ---------------- per-dst softmax + aggregation (one wave per dst) ----------------

template <int H, int D>
__global__ __launch_bounds__(256) void gat_aggregate(const float* __restrict__ feat,
                                                     const float* __restrict__ el,
                                                     const float* __restrict__ er,
                                                     const int* __restrict__ row_start,
                                                     const int* __restrict__ csr_src,
                                                     const float* __restrict__ bias,
                                                     float* __restrict__ out, int N) {
    int dstn = (blockIdx.x * blockDim.x + threadIdx.x) >> 6;
    int lane = threadIdx.x & 63;
    if (dstn >= N) return;
    int beg = row_start[dstn], end = row_start[dstn + 1];

    float er_d[H];
#pragma unroll
    for (int h = 0; h < H; ++h) er_d[h] = er[(size_t)dstn * H + h];

    // pass 1: max over in-edges (lane per edge)
    float m[H];
#pragma unroll
    for (int h = 0; h < H; ++h) m[h] = -INFINITY;
    for (int i = beg + lane; i < end; i += 64) {
        int s = csr_src[i];
#pragma unroll
        for (int h = 0; h < H; ++h) {
            float e = el[(size_t)s * H + h] + er_d[h];
            e = (e > 0.f) ? e : NEG_SLOPE * e;
            m[h] = fmaxf(m[h], e);
        }
    }
#pragma unroll
    for (int h = 0; h < H; ++h)
#pragma unroll
        for (int off = 32; off; off >>= 1) m[h] = fmaxf(m[h], __shfl_xor(m[h], off));

    // pass 2: sum of exp
    float ssum[H];
#pragma unroll
    for (int h = 0; h < H; ++h) ssum[h] = 0.f;
    for (int i = beg + lane; i < end; i += 64) {
        int s = csr_src[i];
#pragma unroll
        for (int h = 0; h < H; ++h) {
            float e = el[(size_t)s * H + h] + er_d[h];
            e = (e > 0.f) ? e : NEG_SLOPE * e;
            ssum[h] += expf(e - m[h]);
        }
    }
#pragma unroll
    for (int h = 0; h < H; ++h)
#pragma unroll
        for (int off = 32; off; off >>= 1) ssum[h] += __shfl_xor(ssum[h], off);

    // pass 3: alpha-weighted feature aggregation (lanes over dims)
    float acc[H];
#pragma unroll
    for (int h = 0; h < H; ++h) acc[h] = 0.f;
    for (int i = beg; i < end; ++i) {
        int s = csr_src[i];
#pragma unroll
        for (int h = 0; h < H; ++h) {
            float e = el[(size_t)s * H + h] + er_d[h];  // broadcast load
            e = (e > 0.f) ? e : NEG_SLOPE * e;
            float alpha = expf(e - m[h]) / ssum[h];
            if (lane < D) acc[h] += feat[(size_t)s * (H * D) + h * D + lane] * alpha;
        }
    }
    if (lane < D) {
#pragma unroll
        for (int h = 0; h < H; ++h)
            out[(size_t)dstn * (H * D) + h * D + lane] = acc[h] + bias[h * D + lane];
    }
}

// ---------------- launch ----------------

extern "C" void kernel_launch(void* const* d_in, const int* in_sizes, int n_in,
                              void* d_out, int out_size, void* d_ws, size_t ws_size,
                              hipStream_t stream) {
    const float* in_feat = (const float*)d_in[0];
    const int*   src     = (const int*)d_in[1];
    const int*   dst     = (const int*)d_in[2];
    const float* W0 = (const float*)d_in[3];
    const float* al0 = (const float*)d_in[4];
    const float* ar0 = (const float*)d_in[5];
    const float* b0 = (const float*)d_in[6];
    const float* W1 = (const float*)d_in[7];
    const float* al1 = (const float*)d_in[8];
    const float* ar1 = (const float*)d_in[9];
    const float* b1 = (const float*)d_in[10];
    const float* W2 = (const float*)d_in[11];
    const float* al2 = (const float*)d_in[12];
    const float* ar2 = (const float*)d_in[13];
    const float* b2 = (const float*)d_in[14];
    float* out = (float*)d_out;

    const int N = in_sizes[0] / 128;  // 50000
    const int E = in_sizes[1];        // 850000

    // workspace carve (256B aligned)
    char* ws = (char*)d_ws;
    auto alloc = [&](size_t bytes) -> void* {
        void* p = (void*)ws;
        ws += (bytes + 255) & ~(size_t)255;
        return p;
    };
    int* deg       = (int*)alloc((size_t)N * 4);
    int* row_start = (int*)alloc((size_t)(N + 1) * 4);
    int* cursor    = (int*)alloc((size_t)N * 4);
    int* csr_src   = (int*)alloc((size_t)E * 4);
    float* feat    = (float*)alloc((size_t)N * 128 * 4);
    float* el      = (float*)alloc((size_t)N * 2 * 4);
    float* er      = (float*)alloc((size_t)N * 2 * 4);
    float* h0      = (float*)alloc((size_t)N * 128 * 4);
    float* h1      = (float*)alloc((size_t)N * 64 * 4);

    hipMemsetAsync(deg, 0, (size_t)N * 4, stream);
    hipMemsetAsync(cursor, 0, (size_t)N * 4, stream);

    int egrid = (E + 255) / 256;
    degree_hist<<<egrid, 256, 0, stream>>>(dst, deg, E);
    exclusive_scan<<<1, 1024, 0, stream>>>(deg, row_start, N);
    scatter_edges<<<egrid, 256, 0, stream>>>(src, dst, row_start, cursor, csr_src, E);

    int ngrid = (N * 64 + 255) / 256;  // one wave per node

    // layer 0: in=128, H=2, D=64
    {
        constexpr int ROWS = (256 / 128) * 8;
        int g = (N + ROWS - 1) / ROWS;
        gemm_feat<128, 128><<<g, 256, 0, stream>>>(in_feat, W0, feat, N);
        attn_scores<2, 64><<<ngrid, 256, 0, stream>>>(feat, al0, ar0, el, er, N);
        gat_aggregate<2, 64><<<ngrid, 256, 0, stream>>>(feat, el, er, row_start, csr_src, b0, h0, N);
    }
    // layer 1: in=128, H=1, D=64 (mean over 1 head = identity)
    {
        constexpr int ROWS = (256 / 64) * 8;
        int g = (N + ROWS - 1) / ROWS;
        gemm_feat<128, 64><<<g, 256, 0, stream>>>(h0, W1, feat, N);
        attn_scores<1, 64><<<ngrid, 256, 0, stream>>>(feat, al1, ar1, el, er, N);
        gat_aggregate<1, 64><<<ngrid, 256, 0, stream>>>(feat, el, er, row_start, csr_src, b1, h1, N);
    }
    // layer 2: in=64, H=1, D=40
    {
        constexpr int ROWS = (256 / 40) * 8;
        int g = (N + ROWS - 1) / ROWS;
        gemm_feat<64, 40><<<g, 256, 0, stream>>>(h1, W2, feat, N);
        attn_scores<1, 40><<<ngrid, 256, 0, stream>>>(feat, al2, ar2, el, er, N);
        gat_aggregate<1, 40><<<ngrid, 256, 0, stream>>>(feat, el, er, row_start, csr_src, b2, out, N);
    }
}

// Round 2
// 549.373 us; speedup vs baseline: 1.2822x; 1.2822x over previous
//
#include <hip/hip_runtime.h>
#include <math.h>

#define NEG_SLOPE 0.2f

// ---------------- CSR build ----------------

__global__ __launch_bounds__(256) void degree_hist(const int* __restrict__ dst,
                                                   int* __restrict__ deg, int E) {
    int e = blockIdx.x * blockDim.x + threadIdx.x;
    if (e < E) atomicAdd(&deg[dst[e]], 1);
}

// single block, 1024 threads; thread-serial chunks + one LDS scan
__global__ __launch_bounds__(1024) void exclusive_scan(const int* __restrict__ in,
                                                       int* __restrict__ out, int n) {
    __shared__ int sums[1024];
    int tid = threadIdx.x;
    int chunk = (n + 1023) / 1024;
    int lo = tid * chunk;
    int hi = (lo + chunk < n) ? lo + chunk : n;
    int s = 0;
    for (int i = lo; i < hi; ++i) s += in[i];
    sums[tid] = s;
    __syncthreads();
    for (int off = 1; off < 1024; off <<= 1) {
        int t = (tid >= off) ? sums[tid - off] : 0;
        __syncthreads();
        sums[tid] += t;
        __syncthreads();
    }
    int run = sums[tid] - s;  // exclusive prefix at chunk start
    for (int i = lo; i < hi; ++i) { out[i] = run; run += in[i]; }
    if (tid == 0) out[n] = sums[1023];
}

// consumes deg (atomicSub to 0) so no separate cursor buffer is needed
__global__ __launch_bounds__(256) void scatter_edges(const int* __restrict__ src,
                                                     const int* __restrict__ dst,
                                                     const int* __restrict__ row_start,
                                                     int* __restrict__ deg,
                                                     int* __restrict__ csr_src, int E) {
    int e = blockIdx.x * blockDim.x + threadIdx.x;
    if (e >= E) return;
    int d = dst[e];
    int pos = atomicSub(&deg[d], 1) - 1;
    csr_src[row_start[d] + pos] = src[e];
}

// ---------------- GEMM (col4 x row8 register blocking) ----------------
// out[N,M] = x[N,K] @ W[K,M]; block = (M/4)*G threads, covers G*RPG rows.

__device__ inline void fma4(float4& a, const float4& w, float xs) {
    a.x += w.x * xs; a.y += w.y * xs; a.z += w.z * xs; a.w += w.w * xs;
}

template <int K, int M, int G, int RPG>
__global__ __launch_bounds__((M / 4) * G) void gemm_feat4(const float* __restrict__ x,
                                                          const float* __restrict__ W,
                                                          float* __restrict__ out, int N) {
    constexpr int CT = M / 4;
    constexpr int ROWS = G * RPG;
    constexpr int NT = CT * G;
    __shared__ float4 sx[ROWS][K / 4];
    const int tid = threadIdx.x;
    const int col4 = tid % CT;
    const int grp = tid / CT;
    const float4* __restrict__ W4 = (const float4*)W;
    const float4* __restrict__ x4 = (const float4*)x;

    for (int base = blockIdx.x * ROWS; base < N; base += gridDim.x * ROWS) {
        __syncthreads();
        for (int i = tid; i < ROWS * (K / 4); i += NT) {
            int r = i / (K / 4), c = i % (K / 4);
            int row = base + r;
            sx[r][c] = (row < N) ? x4[(size_t)row * (K / 4) + c] : float4{0.f, 0.f, 0.f, 0.f};
        }
        __syncthreads();
        float4 acc[RPG];
#pragma unroll
        for (int rr = 0; rr < RPG; ++rr) acc[rr] = float4{0.f, 0.f, 0.f, 0.f};
#pragma unroll 4
        for (int k4 = 0; k4 < K / 4; ++k4) {
            float4 w0 = W4[(size_t)(4 * k4 + 0) * CT + col4];
            float4 w1 = W4[(size_t)(4 * k4 + 1) * CT + col4];
            float4 w2 = W4[(size_t)(4 * k4 + 2) * CT + col4];
            float4 w3 = W4[(size_t)(4 * k4 + 3) * CT + col4];
#pragma unroll
            for (int rr = 0; rr < RPG; ++rr) {
                float4 xv = sx[grp * RPG + rr][k4];
                fma4(acc[rr], w0, xv.x);
                fma4(acc[rr], w1, xv.y);
                fma4(acc[rr], w2, xv.z);
                fma4(acc[rr], w3, xv.w);
            }
        }
#pragma unroll
        for (int rr = 0; rr < RPG; ++rr) {
            int row = base + grp * RPG + rr;
            if (row < N) ((float4*)out)[(size_t)row * CT + col4] = acc[rr];
        }
    }
}

// old scalar-LDS gemm kept for M=40 (layer 2, small)
template <int K, int M>
__global__ __launch_bounds__(256) void gemm_feat(const float* __restrict__ x,
                                                 const float* __restrict__ W,
                                                 float* __restrict__ out, int N) {
    constexpr int NGRP = 256 / M;
    constexpr int RPG = 8;
    constexpr int ROWS = NGRP * RPG;
    __shared__ float sx[ROWS][K];
    const int tid = threadIdx.x;
    const int col = tid % M;
    const int grp = tid / M;
    for (int base = blockIdx.x * ROWS; base < N; base += gridDim.x * ROWS) {
        __syncthreads();
        for (int i = tid; i < ROWS * K; i += 256) {
            int r = i / K, c = i % K;
            int row = base + r;
            sx[r][c] = (row < N) ? x[(size_t)row * K + c] : 0.f;
        }
        __syncthreads();
        if (grp < NGRP) {
            float acc[RPG];
#pragma unroll
            for (int rr = 0; rr < RPG; ++rr) acc[rr] = 0.f;
            for (int k = 0; k < K; ++k) {
                float w = W[(size_t)k * M + col];
#pragma unroll
                for (int rr = 0; rr < RPG; ++rr) acc[rr] += sx[grp * RPG + rr][k] * w;
            }
#pragma unroll
            for (int rr = 0; rr < RPG; ++rr) {
                int row = base + grp * RPG + rr;
                if (row < N) out[(size_t)row * M + col] = acc[rr];
            }
        }
    }
}

// ---------------- attention scores el/er per (node, head) ----------------

template <int H, int D>
__global__ __launch_bounds__(256) void attn_scores(const float* __restrict__ feat,
                                                   const float* __restrict__ al,
                                                   const float* __restrict__ ar,
                                                   float* __restrict__ el,
                                                   float* __restrict__ er, int N) {
    int node = (blockIdx.x * blockDim.x + threadIdx.x) >> 6;
    int lane = threadIdx.x & 63;
    if (node >= N) return;
#pragma unroll
    for (int h = 0; h < H; ++h) {
        float v = 0.f, w = 0.f;
        if (lane < D) {
            float f = feat[(size_t)node * (H * D) + h * D + lane];
            v = f * al[h * D + lane];
            w = f * ar[h * D + lane];
        }
#pragma unroll
        for (int off = 32; off; off >>= 1) {
            v += __shfl_down(v, off);
            w += __shfl_down(w, off);
        }
        if (lane == 0) {
            el[(size_t)node * H + h] = v;
            er[(size_t)node * H + h] = w;
        }
    }
}

// ---------------- per-dst softmax + aggregation (one wave per dst) ----------------
// lane-per-edge score/exp computation, shuffle-broadcast into D-lane FMA;
// un-normalized accumulation, single divide at the end.

template <int H, int D>
__global__ __launch_bounds__(256) void gat_aggregate(const float* __restrict__ feat,
                                                     const float* __restrict__ el,
                                                     const float* __restrict__ er,
                                                     const int* __restrict__ row_start,
                                                     const int* __restrict__ csr_src,
                                                     const float* __restrict__ bias,
                                                     float* __restrict__ out, int N) {
    int dstn = (blockIdx.x * blockDim.x + threadIdx.x) >> 6;
    int lane = threadIdx.x & 63;
    if (dstn >= N) return;
    int beg = row_start[dstn], end = row_start[dstn + 1];

    float er_d[H];
#pragma unroll
    for (int h = 0; h < H; ++h) er_d[h] = er[(size_t)dstn * H + h];

    float acc[H], ssum[H];
#pragma unroll
    for (int h = 0; h < H; ++h) { acc[h] = 0.f; ssum[h] = 0.f; }

    if (end - beg <= 64) {
        // fast path: one edge per lane, scores computed exactly once
        int idx = beg + lane;
        bool valid = idx < end;
        int s = valid ? csr_src[idx] : csr_src[beg];
        float ev[H], m[H], p[H];
#pragma unroll
        for (int h = 0; h < H; ++h) {
            float e = el[(size_t)s * H + h] + er_d[h];
            e = (e > 0.f) ? e : NEG_SLOPE * e;
            ev[h] = e;
            m[h] = valid ? e : -INFINITY;
        }
#pragma unroll
        for (int h = 0; h < H; ++h)
#pragma unroll
            for (int off = 32; off; off >>= 1) m[h] = fmaxf(m[h], __shfl_xor(m[h], off));
#pragma unroll
        for (int h = 0; h < H; ++h) {
            p[h] = valid ? expf(ev[h] - m[h]) : 0.f;
            float t = p[h];
#pragma unroll
            for (int off = 32; off; off >>= 1) t += __shfl_xor(t, off);
            ssum[h] = t;
        }
        int cnt = end - beg;
        for (int j = 0; j < cnt; ++j) {
            int sj = __shfl(s, j);
            const float* fp = feat + (size_t)sj * (H * D);
#pragma unroll
            for (int h = 0; h < H; ++h) {
                float pj = __shfl(p[h], j);
                if (lane < D) acc[h] += fp[h * D + lane] * pj;
            }
        }
    } else {
        // general path: chunked two-pass
        float m[H];
#pragma unroll
        for (int h = 0; h < H; ++h) m[h] = -INFINITY;
        for (int i = beg + lane; i < end; i += 64) {
            int s = csr_src[i];
#pragma unroll
            for (int h = 0; h < H; ++h) {
                float e = el[(size_t)s * H + h] + er_d[h];
                e = (e > 0.f) ? e : NEG_SLOPE * e;
                m[h] = fmaxf(m[h], e);
            }
        }
#pragma unroll
        for (int h = 0; h < H; ++h)
#pragma unroll
            for (int off = 32; off; off >>= 1) m[h] = fmaxf(m[h], __shfl_xor(m[h], off));

        for (int base = beg; base < end; base += 64) {
            int idx = base + lane;
            bool valid = idx < end;
            int s = valid ? csr_src[idx] : csr_src[beg];
            float p[H];
#pragma unroll
            for (int h = 0; h < H; ++h) {
                float e = el[(size_t)s * H + h] + er_d[h];
                e = (e > 0.f) ? e : NEG_SLOPE * e;
                p[h] = valid ? expf(e - m[h]) : 0.f;
                ssum[h] += p[h];
            }
            int cnt = (end - base < 64) ? end - base : 64;
            for (int j = 0; j < cnt; ++j) {
                int sj = __shfl(s, j);
                const float* fp = feat + (size_t)sj * (H * D);
#pragma unroll
                for (int h = 0; h < H; ++h) {
                    float pj = __shfl(p[h], j);
                    if (lane < D) acc[h] += fp[h * D + lane] * pj;
                }
            }
        }
#pragma unroll
        for (int h = 0; h < H; ++h)
#pragma unroll
            for (int off = 32; off; off >>= 1) ssum[h] += __shfl_xor(ssum[h], off);
    }

    if (lane < D) {
#pragma unroll
        for (int h = 0; h < H; ++h)
            out[(size_t)dstn * (H * D) + h * D + lane] = acc[h] / ssum[h] + bias[h * D + lane];
    }
}

// ---------------- launch ----------------

extern "C" void kernel_launch(void* const* d_in, const int* in_sizes, int n_in,
                              void* d_out, int out_size, void* d_ws, size_t ws_size,
                              hipStream_t stream) {
    const float* in_feat = (const float*)d_in[0];
    const int*   src     = (const int*)d_in[1];
    const int*   dst     = (const int*)d_in[2];
    const float* W0 = (const float*)d_in[3];
    const float* al0 = (const float*)d_in[4];
    const float* ar0 = (const float*)d_in[5];
    const float* b0 = (const float*)d_in[6];
    const float* W1 = (const float*)d_in[7];
    const float* al1 = (const float*)d_in[8];
    const float* ar1 = (const float*)d_in[9];
    const float* b1 = (const float*)d_in[10];
    const float* W2 = (const float*)d_in[11];
    const float* al2 = (const float*)d_in[12];
    const float* ar2 = (const float*)d_in[13];
    const float* b2 = (const float*)d_in[14];
    float* out = (float*)d_out;

    const int N = in_sizes[0] / 128;  // 50000
    const int E = in_sizes[1];        // 850000

    char* ws = (char*)d_ws;
    auto alloc = [&](size_t bytes) -> void* {
        void* p = (void*)ws;
        ws += (bytes + 255) & ~(size_t)255;
        return p;
    };
    int* deg       = (int*)alloc((size_t)N * 4);
    int* row_start = (int*)alloc((size_t)(N + 1) * 4);
    int* csr_src   = (int*)alloc((size_t)E * 4);
    float* feat    = (float*)alloc((size_t)N * 128 * 4);
    float* el      = (float*)alloc((size_t)N * 2 * 4);
    float* er      = (float*)alloc((size_t)N * 2 * 4);
    float* h0      = (float*)alloc((size_t)N * 128 * 4);
    float* h1      = (float*)alloc((size_t)N * 64 * 4);

    hipMemsetAsync(deg, 0, (size_t)N * 4, stream);

    int egrid = (E + 255) / 256;
    degree_hist<<<egrid, 256, 0, stream>>>(dst, deg, E);
    exclusive_scan<<<1, 1024, 0, stream>>>(deg, row_start, N);
    scatter_edges<<<egrid, 256, 0, stream>>>(src, dst, row_start, deg, csr_src, E);

    int ngrid = (N * 64 + 255) / 256;  // one wave per node

    // layer 0: in=128, H=2, D=64
    {
        int g = (N + 63) / 64;
        gemm_feat4<128, 128, 8, 8><<<g, 256, 0, stream>>>(in_feat, W0, feat, N);
        attn_scores<2, 64><<<ngrid, 256, 0, stream>>>(feat, al0, ar0, el, er, N);
        gat_aggregate<2, 64><<<ngrid, 256, 0, stream>>>(feat, el, er, row_start, csr_src, b0, h0, N);
    }
    // layer 1: in=128, H=1, D=64
    {
        int g = (N + 63) / 64;
        gemm_feat4<128, 64, 16, 4><<<g, 256, 0, stream>>>(h0, W1, feat, N);
        attn_scores<1, 64><<<ngrid, 256, 0, stream>>>(feat, al1, ar1, el, er, N);
        gat_aggregate<1, 64><<<ngrid, 256, 0, stream>>>(feat, el, er, row_start, csr_src, b1, h1, N);
    }
    // layer 2: in=64, H=1, D=40
    {
        constexpr int ROWS = (256 / 40) * 8;
        int g = (N + ROWS - 1) / ROWS;
        gemm_feat<64, 40><<<g, 256, 0, stream>>>(h1, W2, feat, N);
        attn_scores<1, 40><<<ngrid, 256, 0, stream>>>(feat, al2, ar2, el, er, N);
        gat_aggregate<1, 40><<<ngrid, 256, 0, stream>>>(feat, el, er, row_start, csr_src, b2, out, N);
    }
}

// Round 3
// 424.028 us; speedup vs baseline: 1.6613x; 1.2956x over previous
//
#include <hip/hip_runtime.h>
#include <math.h>

#define NEG_SLOPE 0.2f

// ---------------- CSR build ----------------

__global__ __launch_bounds__(256) void degree_hist(const int* __restrict__ dst,
                                                   int* __restrict__ deg, int E) {
    int e = blockIdx.x * blockDim.x + threadIdx.x;
    if (e < E) atomicAdd(&deg[dst[e]], 1);
}

// ---- parallel exclusive scan: 3 stages ----
// A: per-block (256-elem) sums
__global__ __launch_bounds__(256) void scan_block_sums(const int* __restrict__ in,
                                                       int* __restrict__ partial, int n) {
    int i = blockIdx.x * 256 + threadIdx.x;
    int v = (i < n) ? in[i] : 0;
#pragma unroll
    for (int off = 32; off; off >>= 1) v += __shfl_xor(v, off);
    __shared__ int wsum[4];
    if ((threadIdx.x & 63) == 0) wsum[threadIdx.x >> 6] = v;
    __syncthreads();
    if (threadIdx.x == 0) partial[blockIdx.x] = wsum[0] + wsum[1] + wsum[2] + wsum[3];
}

// B: single block scans <=256 partials, writes exclusive offsets + total
__global__ __launch_bounds__(256) void scan_offsets(const int* __restrict__ partial,
                                                    int* __restrict__ partial_scan,
                                                    int* __restrict__ total_out, int nb) {
    __shared__ int buf[256];
    int t = threadIdx.x;
    int v = (t < nb) ? partial[t] : 0;
    buf[t] = v;
    __syncthreads();
    for (int off = 1; off < 256; off <<= 1) {
        int x = (t >= off) ? buf[t - off] : 0;
        __syncthreads();
        buf[t] += x;
        __syncthreads();
    }
    partial_scan[t] = buf[t] - v;
    if (t == 255) *total_out = buf[255];
}

// C: per-block exclusive scan + block offset
__global__ __launch_bounds__(256) void scan_final(const int* __restrict__ in,
                                                  const int* __restrict__ partial_scan,
                                                  int* __restrict__ out, int n) {
    __shared__ int buf[256];
    int t = threadIdx.x;
    int i = blockIdx.x * 256 + t;
    int v = (i < n) ? in[i] : 0;
    buf[t] = v;
    __syncthreads();
    for (int off = 1; off < 256; off <<= 1) {
        int x = (t >= off) ? buf[t - off] : 0;
        __syncthreads();
        buf[t] += x;
        __syncthreads();
    }
    if (i < n) out[i] = partial_scan[blockIdx.x] + buf[t] - v;
}

// consumes deg (atomicSub to 0) so no separate cursor buffer is needed
__global__ __launch_bounds__(256) void scatter_edges(const int* __restrict__ src,
                                                     const int* __restrict__ dst,
                                                     const int* __restrict__ row_start,
                                                     int* __restrict__ deg,
                                                     int* __restrict__ csr_src, int E) {
    int e = blockIdx.x * blockDim.x + threadIdx.x;
    if (e >= E) return;
    int d = dst[e];
    int pos = atomicSub(&deg[d], 1) - 1;
    csr_src[row_start[d] + pos] = src[e];
}

// ---------------- GEMM (col4 x row blocking) + fused attn-score epilogue ----
// out[N,M] = x[N,K] @ W[K,M]; also writes el[n,h]=feat·al, er[n,h]=feat·ar.

__device__ inline void fma4(float4& a, const float4& w, float xs) {
    a.x += w.x * xs; a.y += w.y * xs; a.z += w.z * xs; a.w += w.w * xs;
}
__device__ inline float dot4(const float4& a, const float4& b) {
    return a.x * b.x + a.y * b.y + a.z * b.z + a.w * b.w;
}

template <int K, int M, int G, int RPG, int H, int D>
__global__ __launch_bounds__((M / 4) * G) void gemm_feat4(const float* __restrict__ x,
                                                          const float* __restrict__ W,
                                                          const float* __restrict__ al,
                                                          const float* __restrict__ ar,
                                                          float* __restrict__ out,
                                                          float* __restrict__ el,
                                                          float* __restrict__ er, int N) {
    constexpr int CT = M / 4;          // col-groups (threads per row)
    constexpr int LPH = D / 4;         // lanes per head (16 for D=64)
    constexpr int ROWS = G * RPG;
    constexpr int NT = CT * G;
    static_assert(LPH == 16 && (CT % LPH) == 0, "epilogue assumes 16-lane head groups");
    __shared__ float4 sx[ROWS][K / 4];
    const int tid = threadIdx.x;
    const int col4 = tid % CT;
    const int grp = tid / CT;
    const int h = col4 / LPH;
    const float4* __restrict__ W4 = (const float4*)W;
    const float4* __restrict__ x4 = (const float4*)x;
    const float4 av = ((const float4*)al)[col4];
    const float4 rv = ((const float4*)ar)[col4];

    for (int base = blockIdx.x * ROWS; base < N; base += gridDim.x * ROWS) {
        __syncthreads();
        for (int i = tid; i < ROWS * (K / 4); i += NT) {
            int r = i / (K / 4), c = i % (K / 4);
            int row = base + r;
            sx[r][c] = (row < N) ? x4[(size_t)row * (K / 4) + c] : float4{0.f, 0.f, 0.f, 0.f};
        }
        __syncthreads();
        float4 acc[RPG];
#pragma unroll
        for (int rr = 0; rr < RPG; ++rr) acc[rr] = float4{0.f, 0.f, 0.f, 0.f};
#pragma unroll 4
        for (int k4 = 0; k4 < K / 4; ++k4) {
            float4 w0 = W4[(size_t)(4 * k4 + 0) * CT + col4];
            float4 w1 = W4[(size_t)(4 * k4 + 1) * CT + col4];
            float4 w2 = W4[(size_t)(4 * k4 + 2) * CT + col4];
            float4 w3 = W4[(size_t)(4 * k4 + 3) * CT + col4];
#pragma unroll
            for (int rr = 0; rr < RPG; ++rr) {
                float4 xv = sx[grp * RPG + rr][k4];
                fma4(acc[rr], w0, xv.x);
                fma4(acc[rr], w1, xv.y);
                fma4(acc[rr], w2, xv.z);
                fma4(acc[rr], w3, xv.w);
            }
        }
#pragma unroll
        for (int rr = 0; rr < RPG; ++rr) {
            int row = base + grp * RPG + rr;
            if (row < N) ((float4*)out)[(size_t)row * CT + col4] = acc[rr];
        }
        // fused attn scores: el/er = row-wise dot with al/ar, 16-lane reduce
#pragma unroll
        for (int rr = 0; rr < RPG; ++rr) {
            float pl = dot4(acc[rr], av);
            float pr = dot4(acc[rr], rv);
#pragma unroll
            for (int off = 1; off < LPH; off <<= 1) {
                pl += __shfl_xor(pl, off);
                pr += __shfl_xor(pr, off);
            }
            if ((col4 % LPH) == 0) {
                int row = base + grp * RPG + rr;
                if (row < N) {
                    el[(size_t)row * H + h] = pl;
                    er[(size_t)row * H + h] = pr;
                }
            }
        }
    }
}

// scalar-LDS gemm for M=40 (layer 2) with LDS-atomic attn epilogue (H=1)
template <int K, int M>
__global__ __launch_bounds__(256) void gemm_feat(const float* __restrict__ x,
                                                 const float* __restrict__ W,
                                                 const float* __restrict__ al,
                                                 const float* __restrict__ ar,
                                                 float* __restrict__ out,
                                                 float* __restrict__ el,
                                                 float* __restrict__ er, int N) {
    constexpr int NGRP = 256 / M;
    constexpr int RPG = 8;
    constexpr int ROWS = NGRP * RPG;
    __shared__ float sx[ROWS][K];
    __shared__ float sel[ROWS], ser[ROWS];
    const int tid = threadIdx.x;
    const int col = tid % M;
    const int grp = tid / M;
    for (int base = blockIdx.x * ROWS; base < N; base += gridDim.x * ROWS) {
        __syncthreads();
        for (int i = tid; i < ROWS * K; i += 256) {
            int r = i / K, c = i % K;
            int row = base + r;
            sx[r][c] = (row < N) ? x[(size_t)row * K + c] : 0.f;
        }
        if (tid < ROWS) { sel[tid] = 0.f; ser[tid] = 0.f; }
        __syncthreads();
        if (grp < NGRP) {
            float acc[RPG];
#pragma unroll
            for (int rr = 0; rr < RPG; ++rr) acc[rr] = 0.f;
            for (int k = 0; k < K; ++k) {
                float w = W[(size_t)k * M + col];
#pragma unroll
                for (int rr = 0; rr < RPG; ++rr) acc[rr] += sx[grp * RPG + rr][k] * w;
            }
            float alc = al[col], arc = ar[col];
#pragma unroll
            for (int rr = 0; rr < RPG; ++rr) {
                int row = base + grp * RPG + rr;
                if (row < N) out[(size_t)row * M + col] = acc[rr];
                atomicAdd(&sel[grp * RPG + rr], acc[rr] * alc);
                atomicAdd(&ser[grp * RPG + rr], acc[rr] * arc);
            }
        }
        __syncthreads();
        if (tid < ROWS) {
            int row = base + tid;
            if (row < N) { el[row] = sel[tid]; er[row] = ser[tid]; }
        }
    }
}

// ---------------- per-dst softmax + aggregation (one wave per dst) ----------------

template <int H, int D>
__global__ __launch_bounds__(256) void gat_aggregate(const float* __restrict__ feat,
                                                     const float* __restrict__ el,
                                                     const float* __restrict__ er,
                                                     const int* __restrict__ row_start,
                                                     const int* __restrict__ csr_src,
                                                     const float* __restrict__ bias,
                                                     float* __restrict__ out, int N) {
    int dstn = (blockIdx.x * blockDim.x + threadIdx.x) >> 6;
    int lane = threadIdx.x & 63;
    if (dstn >= N) return;
    int beg = row_start[dstn], end = row_start[dstn + 1];

    float er_d[H];
#pragma unroll
    for (int h = 0; h < H; ++h) er_d[h] = er[(size_t)dstn * H + h];

    float acc[H], ssum[H];
#pragma unroll
    for (int h = 0; h < H; ++h) { acc[h] = 0.f; ssum[h] = 0.f; }

    if (end - beg <= 64) {
        // fast path: one edge per lane
        int idx = beg + lane;
        bool valid = idx < end;
        int s = valid ? csr_src[idx] : csr_src[beg];
        float ev[H], m[H], p[H];
#pragma unroll
        for (int h = 0; h < H; ++h) {
            float e = el[(size_t)s * H + h] + er_d[h];
            e = (e > 0.f) ? e : NEG_SLOPE * e;
            ev[h] = e;
            m[h] = valid ? e : -INFINITY;
        }
#pragma unroll
        for (int h = 0; h < H; ++h)
#pragma unroll
            for (int off = 32; off; off >>= 1) m[h] = fmaxf(m[h], __shfl_xor(m[h], off));
#pragma unroll
        for (int h = 0; h < H; ++h) {
            p[h] = valid ? expf(ev[h] - m[h]) : 0.f;
            float t = p[h];
#pragma unroll
            for (int off = 32; off; off >>= 1) t += __shfl_xor(t, off);
            ssum[h] = t;
        }
        int cnt = end - beg;
        int j = 0;
        for (; j + 4 <= cnt; j += 4) {
            int s0 = __shfl(s, j), s1 = __shfl(s, j + 1);
            int s2 = __shfl(s, j + 2), s3 = __shfl(s, j + 3);
            const float* f0 = feat + (size_t)s0 * (H * D);
            const float* f1 = feat + (size_t)s1 * (H * D);
            const float* f2 = feat + (size_t)s2 * (H * D);
            const float* f3 = feat + (size_t)s3 * (H * D);
#pragma unroll
            for (int h = 0; h < H; ++h) {
                float p0 = __shfl(p[h], j), p1 = __shfl(p[h], j + 1);
                float p2 = __shfl(p[h], j + 2), p3 = __shfl(p[h], j + 3);
                float v0 = 0.f, v1 = 0.f, v2 = 0.f, v3 = 0.f;
                if (lane < D) {
                    v0 = f0[h * D + lane]; v1 = f1[h * D + lane];
                    v2 = f2[h * D + lane]; v3 = f3[h * D + lane];
                }
                acc[h] += v0 * p0;
                acc[h] += v1 * p1;
                acc[h] += v2 * p2;
                acc[h] += v3 * p3;
            }
        }
        for (; j < cnt; ++j) {
            int sj = __shfl(s, j);
            const float* fp = feat + (size_t)sj * (H * D);
#pragma unroll
            for (int h = 0; h < H; ++h) {
                float pj = __shfl(p[h], j);
                if (lane < D) acc[h] += fp[h * D + lane] * pj;
            }
        }
    } else {
        // general path: chunked two-pass
        float m[H];
#pragma unroll
        for (int h = 0; h < H; ++h) m[h] = -INFINITY;
        for (int i = beg + lane; i < end; i += 64) {
            int s = csr_src[i];
#pragma unroll
            for (int h = 0; h < H; ++h) {
                float e = el[(size_t)s * H + h] + er_d[h];
                e = (e > 0.f) ? e : NEG_SLOPE * e;
                m[h] = fmaxf(m[h], e);
            }
        }
#pragma unroll
        for (int h = 0; h < H; ++h)
#pragma unroll
            for (int off = 32; off; off >>= 1) m[h] = fmaxf(m[h], __shfl_xor(m[h], off));

        for (int base = beg; base < end; base += 64) {
            int idx = base + lane;
            bool valid = idx < end;
            int s = valid ? csr_src[idx] : csr_src[beg];
            float p[H];
#pragma unroll
            for (int h = 0; h < H; ++h) {
                float e = el[(size_t)s * H + h] + er_d[h];
                e = (e > 0.f) ? e : NEG_SLOPE * e;
                p[h] = valid ? expf(e - m[h]) : 0.f;
                ssum[h] += p[h];
            }
            int cnt = (end - base < 64) ? end - base : 64;
            for (int j = 0; j < cnt; ++j) {
                int sj = __shfl(s, j);
                const float* fp = feat + (size_t)sj * (H * D);
#pragma unroll
                for (int h = 0; h < H; ++h) {
                    float pj = __shfl(p[h], j);
                    if (lane < D) acc[h] += fp[h * D + lane] * pj;
                }
            }
        }
#pragma unroll
        for (int h = 0; h < H; ++h)
#pragma unroll
            for (int off = 32; off; off >>= 1) ssum[h] += __shfl_xor(ssum[h], off);
    }

    if (lane < D) {
#pragma unroll
        for (int h = 0; h < H; ++h)
            out[(size_t)dstn * (H * D) + h * D + lane] = acc[h] / ssum[h] + bias[h * D + lane];
    }
}

// ---------------- launch ----------------

extern "C" void kernel_launch(void* const* d_in, const int* in_sizes, int n_in,
                              void* d_out, int out_size, void* d_ws, size_t ws_size,
                              hipStream_t stream) {
    const float* in_feat = (const float*)d_in[0];
    const int*   src     = (const int*)d_in[1];
    const int*   dst     = (const int*)d_in[2];
    const float* W0 = (const float*)d_in[3];
    const float* al0 = (const float*)d_in[4];
    const float* ar0 = (const float*)d_in[5];
    const float* b0 = (const float*)d_in[6];
    const float* W1 = (const float*)d_in[7];
    const float* al1 = (const float*)d_in[8];
    const float* ar1 = (const float*)d_in[9];
    const float* b1 = (const float*)d_in[10];
    const float* W2 = (const float*)d_in[11];
    const float* al2 = (const float*)d_in[12];
    const float* ar2 = (const float*)d_in[13];
    const float* b2 = (const float*)d_in[14];
    float* out = (float*)d_out;

    const int N = in_sizes[0] / 128;  // 50000
    const int E = in_sizes[1];        // 850000

    char* ws = (char*)d_ws;
    auto alloc = [&](size_t bytes) -> void* {
        void* p = (void*)ws;
        ws += (bytes + 255) & ~(size_t)255;
        return p;
    };
    int* deg       = (int*)alloc((size_t)N * 4);
    int* row_start = (int*)alloc((size_t)(N + 1) * 4);
    int* csr_src   = (int*)alloc((size_t)E * 4);
    int* partial      = (int*)alloc(256 * 4);
    int* partial_scan = (int*)alloc(256 * 4);
    float* feat    = (float*)alloc((size_t)N * 128 * 4);
    float* el      = (float*)alloc((size_t)N * 2 * 4);
    float* er      = (float*)alloc((size_t)N * 2 * 4);
    float* h0      = (float*)alloc((size_t)N * 128 * 4);
    float* h1      = (float*)alloc((size_t)N * 64 * 4);

    hipMemsetAsync(deg, 0, (size_t)N * 4, stream);

    int egrid = (E + 255) / 256;
    degree_hist<<<egrid, 256, 0, stream>>>(dst, deg, E);
    int nb = (N + 255) / 256;  // 196 <= 256
    scan_block_sums<<<nb, 256, 0, stream>>>(deg, partial, N);
    scan_offsets<<<1, 256, 0, stream>>>(partial, partial_scan, &row_start[N], nb);
    scan_final<<<nb, 256, 0, stream>>>(deg, partial_scan, row_start, N);
    scatter_edges<<<egrid, 256, 0, stream>>>(src, dst, row_start, deg, csr_src, E);

    int ngrid = (N * 64 + 255) / 256;  // one wave per node

    // layer 0: in=128, H=2, D=64
    {
        int g = (N + 63) / 64;
        gemm_feat4<128, 128, 8, 8, 2, 64><<<g, 256, 0, stream>>>(in_feat, W0, al0, ar0, feat, el, er, N);
        gat_aggregate<2, 64><<<ngrid, 256, 0, stream>>>(feat, el, er, row_start, csr_src, b0, h0, N);
    }
    // layer 1: in=128, H=1, D=64
    {
        int g = (N + 63) / 64;
        gemm_feat4<128, 64, 16, 4, 1, 64><<<g, 256, 0, stream>>>(h0, W1, al1, ar1, feat, el, er, N);
        gat_aggregate<1, 64><<<ngrid, 256, 0, stream>>>(feat, el, er, row_start, csr_src, b1, h1, N);
    }
    // layer 2: in=64, H=1, D=40
    {
        constexpr int ROWS = (256 / 40) * 8;
        int g = (N + ROWS - 1) / ROWS;
        gemm_feat<64, 40><<<g, 256, 0, stream>>>(h1, W2, al2, ar2, feat, el, er, N);
        gat_aggregate<1, 40><<<ngrid, 256, 0, stream>>>(feat, el, er, row_start, csr_src, b2, out, N);
    }
}

// Round 4
// 413.145 us; speedup vs baseline: 1.7050x; 1.0263x over previous
//
#include <hip/hip_runtime.h>
#include <math.h>

#define NEG_SLOPE 0.2f

// ---------------- CSR build ----------------

__global__ __launch_bounds__(256) void degree_hist(const int* __restrict__ dst,
                                                   int* __restrict__ deg, int E) {
    int e = blockIdx.x * blockDim.x + threadIdx.x;
    if (e < E) atomicAdd(&deg[dst[e]], 1);
}

// ---- parallel exclusive scan: 3 stages ----
__global__ __launch_bounds__(256) void scan_block_sums(const int* __restrict__ in,
                                                       int* __restrict__ partial, int n) {
    int i = blockIdx.x * 256 + threadIdx.x;
    int v = (i < n) ? in[i] : 0;
#pragma unroll
    for (int off = 32; off; off >>= 1) v += __shfl_xor(v, off);
    __shared__ int wsum[4];
    if ((threadIdx.x & 63) == 0) wsum[threadIdx.x >> 6] = v;
    __syncthreads();
    if (threadIdx.x == 0) partial[blockIdx.x] = wsum[0] + wsum[1] + wsum[2] + wsum[3];
}

__global__ __launch_bounds__(256) void scan_offsets(const int* __restrict__ partial,
                                                    int* __restrict__ partial_scan,
                                                    int* __restrict__ total_out, int nb) {
    __shared__ int buf[256];
    int t = threadIdx.x;
    int v = (t < nb) ? partial[t] : 0;
    buf[t] = v;
    __syncthreads();
    for (int off = 1; off < 256; off <<= 1) {
        int x = (t >= off) ? buf[t - off] : 0;
        __syncthreads();
        buf[t] += x;
        __syncthreads();
    }
    partial_scan[t] = buf[t] - v;
    if (t == 255) *total_out = buf[255];
}

__global__ __launch_bounds__(256) void scan_final(const int* __restrict__ in,
                                                  const int* __restrict__ partial_scan,
                                                  int* __restrict__ out, int n) {
    __shared__ int buf[256];
    int t = threadIdx.x;
    int i = blockIdx.x * 256 + t;
    int v = (i < n) ? in[i] : 0;
    buf[t] = v;
    __syncthreads();
    for (int off = 1; off < 256; off <<= 1) {
        int x = (t >= off) ? buf[t - off] : 0;
        __syncthreads();
        buf[t] += x;
        __syncthreads();
    }
    if (i < n) out[i] = partial_scan[blockIdx.x] + buf[t] - v;
}

__global__ __launch_bounds__(256) void scatter_edges(const int* __restrict__ src,
                                                     const int* __restrict__ dst,
                                                     const int* __restrict__ row_start,
                                                     int* __restrict__ deg,
                                                     int* __restrict__ csr_src, int E) {
    int e = blockIdx.x * blockDim.x + threadIdx.x;
    if (e >= E) return;
    int d = dst[e];
    int pos = atomicSub(&deg[d], 1) - 1;
    csr_src[row_start[d] + pos] = src[e];
}

// ---------------- GEMM (col4 x row blocking) + fused attn-score epilogue ----

__device__ inline void fma4(float4& a, const float4& w, float xs) {
    a.x += w.x * xs; a.y += w.y * xs; a.z += w.z * xs; a.w += w.w * xs;
}
__device__ inline float dot4(const float4& a, const float4& b) {
    return a.x * b.x + a.y * b.y + a.z * b.z + a.w * b.w;
}

template <int K, int M, int G, int RPG, int H, int D>
__global__ __launch_bounds__((M / 4) * G) void gemm_feat4(const float* __restrict__ x,
                                                          const float* __restrict__ W,
                                                          const float* __restrict__ al,
                                                          const float* __restrict__ ar,
                                                          float* __restrict__ out,
                                                          float* __restrict__ el,
                                                          float* __restrict__ er, int N) {
    constexpr int CT = M / 4;
    constexpr int LPH = D / 4;
    constexpr int ROWS = G * RPG;
    constexpr int NT = CT * G;
    static_assert(LPH == 16 && (CT % LPH) == 0, "epilogue assumes 16-lane head groups");
    __shared__ float4 sx[ROWS][K / 4];
    const int tid = threadIdx.x;
    const int col4 = tid % CT;
    const int grp = tid / CT;
    const int h = col4 / LPH;
    const float4* __restrict__ W4 = (const float4*)W;
    const float4* __restrict__ x4 = (const float4*)x;
    const float4 av = ((const float4*)al)[col4];
    const float4 rv = ((const float4*)ar)[col4];

    for (int base = blockIdx.x * ROWS; base < N; base += gridDim.x * ROWS) {
        __syncthreads();
        for (int i = tid; i < ROWS * (K / 4); i += NT) {
            int r = i / (K / 4), c = i % (K / 4);
            int row = base + r;
            sx[r][c] = (row < N) ? x4[(size_t)row * (K / 4) + c] : float4{0.f, 0.f, 0.f, 0.f};
        }
        __syncthreads();
        float4 acc[RPG];
#pragma unroll
        for (int rr = 0; rr < RPG; ++rr) acc[rr] = float4{0.f, 0.f, 0.f, 0.f};
#pragma unroll 4
        for (int k4 = 0; k4 < K / 4; ++k4) {
            float4 w0 = W4[(size_t)(4 * k4 + 0) * CT + col4];
            float4 w1 = W4[(size_t)(4 * k4 + 1) * CT + col4];
            float4 w2 = W4[(size_t)(4 * k4 + 2) * CT + col4];
            float4 w3 = W4[(size_t)(4 * k4 + 3) * CT + col4];
#pragma unroll
            for (int rr = 0; rr < RPG; ++rr) {
                float4 xv = sx[grp * RPG + rr][k4];
                fma4(acc[rr], w0, xv.x);
                fma4(acc[rr], w1, xv.y);
                fma4(acc[rr], w2, xv.z);
                fma4(acc[rr], w3, xv.w);
            }
        }
#pragma unroll
        for (int rr = 0; rr < RPG; ++rr) {
            int row = base + grp * RPG + rr;
            if (row < N) ((float4*)out)[(size_t)row * CT + col4] = acc[rr];
        }
#pragma unroll
        for (int rr = 0; rr < RPG; ++rr) {
            float pl = dot4(acc[rr], av);
            float pr = dot4(acc[rr], rv);
#pragma unroll
            for (int off = 1; off < LPH; off <<= 1) {
                pl += __shfl_xor(pl, off);
                pr += __shfl_xor(pr, off);
            }
            if ((col4 % LPH) == 0) {
                int row = base + grp * RPG + rr;
                if (row < N) {
                    el[(size_t)row * H + h] = pl;
                    er[(size_t)row * H + h] = pr;
                }
            }
        }
    }
}

// scalar-LDS gemm for M=40 (layer 2) with LDS-atomic attn epilogue (H=1)
template <int K, int M>
__global__ __launch_bounds__(256) void gemm_feat(const float* __restrict__ x,
                                                 const float* __restrict__ W,
                                                 const float* __restrict__ al,
                                                 const float* __restrict__ ar,
                                                 float* __restrict__ out,
                                                 float* __restrict__ el,
                                                 float* __restrict__ er, int N) {
    constexpr int NGRP = 256 / M;
    constexpr int RPG = 8;
    constexpr int ROWS = NGRP * RPG;
    __shared__ float sx[ROWS][K];
    __shared__ float sel[ROWS], ser[ROWS];
    const int tid = threadIdx.x;
    const int col = tid % M;
    const int grp = tid / M;
    for (int base = blockIdx.x * ROWS; base < N; base += gridDim.x * ROWS) {
        __syncthreads();
        for (int i = tid; i < ROWS * K; i += 256) {
            int r = i / K, c = i % K;
            int row = base + r;
            sx[r][c] = (row < N) ? x[(size_t)row * K + c] : 0.f;
        }
        if (tid < ROWS) { sel[tid] = 0.f; ser[tid] = 0.f; }
        __syncthreads();
        if (grp < NGRP) {
            float acc[RPG];
#pragma unroll
            for (int rr = 0; rr < RPG; ++rr) acc[rr] = 0.f;
            for (int k = 0; k < K; ++k) {
                float w = W[(size_t)k * M + col];
#pragma unroll
                for (int rr = 0; rr < RPG; ++rr) acc[rr] += sx[grp * RPG + rr][k] * w;
            }
            float alc = al[col], arc = ar[col];
#pragma unroll
            for (int rr = 0; rr < RPG; ++rr) {
                int row = base + grp * RPG + rr;
                if (row < N) out[(size_t)row * M + col] = acc[rr];
                atomicAdd(&sel[grp * RPG + rr], acc[rr] * alc);
                atomicAdd(&ser[grp * RPG + rr], acc[rr] * arc);
            }
        }
        __syncthreads();
        if (tid < ROWS) {
            int row = base + tid;
            if (row < N) { el[row] = sel[tid]; er[row] = ser[tid]; }
        }
    }
}

// ---------------- per-dst softmax + aggregation (one wave per dst) ----------------
// Quad-split gather: 4 x 16-lane groups each fetch a different edge's feat row
// as float4s -> 4 rows in flight per VMEM instruction.

template <int H, int D>
__global__ __launch_bounds__(256) void gat_aggregate(const float* __restrict__ feat,
                                                     const float* __restrict__ el,
                                                     const float* __restrict__ er,
                                                     const int* __restrict__ row_start,
                                                     const int* __restrict__ csr_src,
                                                     const float* __restrict__ bias,
                                                     float* __restrict__ out, int N) {
    constexpr int Q = D / 4;  // float4s per head row (16 for D=64, 10 for D=40)
    int dstn = (blockIdx.x * blockDim.x + threadIdx.x) >> 6;
    int lane = threadIdx.x & 63;
    if (dstn >= N) return;
    int beg = row_start[dstn], end = row_start[dstn + 1];
    int cnt = end - beg;

    float er_d[H];
#pragma unroll
    for (int h = 0; h < H; ++h) er_d[h] = er[(size_t)dstn * H + h];

    float ssum[H];
    float4 acc[H];
#pragma unroll
    for (int h = 0; h < H; ++h) { ssum[h] = 0.f; acc[h] = float4{0.f, 0.f, 0.f, 0.f}; }

    const int g = lane >> 4;    // edge-group 0..3
    const int ln = lane & 15;   // quad within row

    if (cnt <= 64) {
        // scores: one edge per lane
        int idx = beg + lane;
        bool valid = idx < end;
        int s = valid ? csr_src[idx] : csr_src[beg];
        float ev[H], m[H], p[H];
        if constexpr (H == 2) {
            float2 e2 = ((const float2*)el)[s];
            ev[0] = e2.x + er_d[0];
            ev[1] = e2.y + er_d[1];
        } else {
            ev[0] = el[s] + er_d[0];
        }
#pragma unroll
        for (int h = 0; h < H; ++h) {
            float e = ev[h];
            e = (e > 0.f) ? e : NEG_SLOPE * e;
            ev[h] = e;
            m[h] = valid ? e : -INFINITY;
        }
#pragma unroll
        for (int h = 0; h < H; ++h)
#pragma unroll
            for (int off = 32; off; off >>= 1) m[h] = fmaxf(m[h], __shfl_xor(m[h], off));
#pragma unroll
        for (int h = 0; h < H; ++h) {
            p[h] = valid ? expf(ev[h] - m[h]) : 0.f;
            ssum[h] = p[h];
        }
        // gather: 2x4 edges per iteration (8 per j-step)
        for (int j = 0; j < cnt; j += 8) {
            int sA = __shfl(s, j + g);
            int sB = __shfl(s, j + 4 + g);
            const float4* fA = (const float4*)(feat + (size_t)sA * (H * D));
            const float4* fB = (const float4*)(feat + (size_t)sB * (H * D));
#pragma unroll
            for (int h = 0; h < H; ++h) {
                float pA = __shfl(p[h], j + g);
                float pB = __shfl(p[h], j + 4 + g);
                float4 vA{0.f, 0.f, 0.f, 0.f}, vB{0.f, 0.f, 0.f, 0.f};
                if (Q == 16 || ln < Q) { vA = fA[h * Q + ln]; vB = fB[h * Q + ln]; }
                fma4(acc[h], vA, pA);
                fma4(acc[h], vB, pB);
            }
        }
    } else {
        // general path: pass 1 max, then chunked p + grouped gather
        float m[H];
#pragma unroll
        for (int h = 0; h < H; ++h) m[h] = -INFINITY;
        for (int i = beg + lane; i < end; i += 64) {
            int s = csr_src[i];
            float ev[H];
            if constexpr (H == 2) {
                float2 e2 = ((const float2*)el)[s];
                ev[0] = e2.x + er_d[0];
                ev[1] = e2.y + er_d[1];
            } else {
                ev[0] = el[s] + er_d[0];
            }
#pragma unroll
            for (int h = 0; h < H; ++h) {
                float e = ev[h];
                e = (e > 0.f) ? e : NEG_SLOPE * e;
                m[h] = fmaxf(m[h], e);
            }
        }
#pragma unroll
        for (int h = 0; h < H; ++h)
#pragma unroll
            for (int off = 32; off; off >>= 1) m[h] = fmaxf(m[h], __shfl_xor(m[h], off));

        for (int base = beg; base < end; base += 64) {
            int idx = base + lane;
            bool valid = idx < end;
            int s = valid ? csr_src[idx] : csr_src[beg];
            float p[H];
            float ev[H];
            if constexpr (H == 2) {
                float2 e2 = ((const float2*)el)[s];
                ev[0] = e2.x + er_d[0];
                ev[1] = e2.y + er_d[1];
            } else {
                ev[0] = el[s] + er_d[0];
            }
#pragma unroll
            for (int h = 0; h < H; ++h) {
                float e = ev[h];
                e = (e > 0.f) ? e : NEG_SLOPE * e;
                p[h] = valid ? expf(e - m[h]) : 0.f;
                ssum[h] += p[h];
            }
            int ccnt = (end - base < 64) ? end - base : 64;
            for (int j = 0; j < ccnt; j += 4) {
                int sj = __shfl(s, j + g);
                const float4* fp = (const float4*)(feat + (size_t)sj * (H * D));
#pragma unroll
                for (int h = 0; h < H; ++h) {
                    float pj = __shfl(p[h], j + g);
                    float4 v{0.f, 0.f, 0.f, 0.f};
                    if (Q == 16 || ln < Q) v = fp[h * Q + ln];
                    fma4(acc[h], v, pj);
                }
            }
        }
    }

    // epilogue: reduce ssum across wave, acc across the 4 edge-groups
#pragma unroll
    for (int h = 0; h < H; ++h) {
#pragma unroll
        for (int off = 32; off; off >>= 1) ssum[h] += __shfl_xor(ssum[h], off);
#pragma unroll
        for (int off = 16; off <= 32; off <<= 1) {
            acc[h].x += __shfl_xor(acc[h].x, off);
            acc[h].y += __shfl_xor(acc[h].y, off);
            acc[h].z += __shfl_xor(acc[h].z, off);
            acc[h].w += __shfl_xor(acc[h].w, off);
        }
    }
    if (lane < Q) {
        float4* op = (float4*)(out + (size_t)dstn * (H * D));
        const float4* bp = (const float4*)bias;
#pragma unroll
        for (int h = 0; h < H; ++h) {
            float inv = 1.f / ssum[h];
            float4 bv = bp[h * Q + lane];
            float4 o;
            o.x = acc[h].x * inv + bv.x;
            o.y = acc[h].y * inv + bv.y;
            o.z = acc[h].z * inv + bv.z;
            o.w = acc[h].w * inv + bv.w;
            op[h * Q + lane] = o;
        }
    }
}

// ---------------- launch ----------------

extern "C" void kernel_launch(void* const* d_in, const int* in_sizes, int n_in,
                              void* d_out, int out_size, void* d_ws, size_t ws_size,
                              hipStream_t stream) {
    const float* in_feat = (const float*)d_in[0];
    const int*   src     = (const int*)d_in[1];
    const int*   dst     = (const int*)d_in[2];
    const float* W0 = (const float*)d_in[3];
    const float* al0 = (const float*)d_in[4];
    const float* ar0 = (const float*)d_in[5];
    const float* b0 = (const float*)d_in[6];
    const float* W1 = (const float*)d_in[7];
    const float* al1 = (const float*)d_in[8];
    const float* ar1 = (const float*)d_in[9];
    const float* b1 = (const float*)d_in[10];
    const float* W2 = (const float*)d_in[11];
    const float* al2 = (const float*)d_in[12];
    const float* ar2 = (const float*)d_in[13];
    const float* b2 = (const float*)d_in[14];
    float* out = (float*)d_out;

    const int N = in_sizes[0] / 128;  // 50000
    const int E = in_sizes[1];        // 850000

    char* ws = (char*)d_ws;
    auto alloc = [&](size_t bytes) -> void* {
        void* p = (void*)ws;
        ws += (bytes + 255) & ~(size_t)255;
        return p;
    };
    int* deg       = (int*)alloc((size_t)N * 4);
    int* row_start = (int*)alloc((size_t)(N + 1) * 4);
    int* csr_src   = (int*)alloc((size_t)E * 4);
    int* partial      = (int*)alloc(256 * 4);
    int* partial_scan = (int*)alloc(256 * 4);
    float* feat    = (float*)alloc((size_t)N * 128 * 4);
    float* el      = (float*)alloc((size_t)N * 2 * 4);
    float* er      = (float*)alloc((size_t)N * 2 * 4);
    float* h0      = (float*)alloc((size_t)N * 128 * 4);
    float* h1      = (float*)alloc((size_t)N * 64 * 4);

    hipMemsetAsync(deg, 0, (size_t)N * 4, stream);

    int egrid = (E + 255) / 256;
    degree_hist<<<egrid, 256, 0, stream>>>(dst, deg, E);
    int nb = (N + 255) / 256;
    scan_block_sums<<<nb, 256, 0, stream>>>(deg, partial, N);
    scan_offsets<<<1, 256, 0, stream>>>(partial, partial_scan, &row_start[N], nb);
    scan_final<<<nb, 256, 0, stream>>>(deg, partial_scan, row_start, N);
    scatter_edges<<<egrid, 256, 0, stream>>>(src, dst, row_start, deg, csr_src, E);

    int ngrid = (N * 64 + 255) / 256;  // one wave per node

    // layer 0: in=128, H=2, D=64
    {
        int g = (N + 63) / 64;
        gemm_feat4<128, 128, 8, 8, 2, 64><<<g, 256, 0, stream>>>(in_feat, W0, al0, ar0, feat, el, er, N);
        gat_aggregate<2, 64><<<ngrid, 256, 0, stream>>>(feat, el, er, row_start, csr_src, b0, h0, N);
    }
    // layer 1: in=128, H=1, D=64
    {
        int g = (N + 63) / 64;
        gemm_feat4<128, 64, 16, 4, 1, 64><<<g, 256, 0, stream>>>(h0, W1, al1, ar1, feat, el, er, N);
        gat_aggregate<1, 64><<<ngrid, 256, 0, stream>>>(feat, el, er, row_start, csr_src, b1, h1, N);
    }
    // layer 2: in=64, H=1, D=40
    {
        constexpr int ROWS = (256 / 40) * 8;
        int g = (N + ROWS - 1) / ROWS;
        gemm_feat<64, 40><<<g, 256, 0, stream>>>(h1, W2, al2, ar2, feat, el, er, N);
        gat_aggregate<1, 40><<<ngrid, 256, 0, stream>>>(feat, el, er, row_start, csr_src, b2, out, N);
    }
}

// Round 5
// 406.781 us; speedup vs baseline: 1.7317x; 1.0156x over previous
//
#include <hip/hip_runtime.h>
#include <math.h>

#define NEG_SLOPE 0.2f

// ---------------- CSR build ----------------

__global__ __launch_bounds__(256) void degree_hist(const int* __restrict__ dst,
                                                   int* __restrict__ deg, int E) {
    int e = blockIdx.x * blockDim.x + threadIdx.x;
    if (e < E) atomicAdd(&deg[dst[e]], 1);
}

// ---- parallel exclusive scan: 3 stages ----
__global__ __launch_bounds__(256) void scan_block_sums(const int* __restrict__ in,
                                                       int* __restrict__ partial, int n) {
    int i = blockIdx.x * 256 + threadIdx.x;
    int v = (i < n) ? in[i] : 0;
#pragma unroll
    for (int off = 32; off; off >>= 1) v += __shfl_xor(v, off);
    __shared__ int wsum[4];
    if ((threadIdx.x & 63) == 0) wsum[threadIdx.x >> 6] = v;
    __syncthreads();
    if (threadIdx.x == 0) partial[blockIdx.x] = wsum[0] + wsum[1] + wsum[2] + wsum[3];
}

__global__ __launch_bounds__(256) void scan_offsets(const int* __restrict__ partial,
                                                    int* __restrict__ partial_scan,
                                                    int* __restrict__ total_out, int nb) {
    __shared__ int buf[256];
    int t = threadIdx.x;
    int v = (t < nb) ? partial[t] : 0;
    buf[t] = v;
    __syncthreads();
    for (int off = 1; off < 256; off <<= 1) {
        int x = (t >= off) ? buf[t - off] : 0;
        __syncthreads();
        buf[t] += x;
        __syncthreads();
    }
    partial_scan[t] = buf[t] - v;
    if (t == 255) *total_out = buf[255];
}

__global__ __launch_bounds__(256) void scan_final(const int* __restrict__ in,
                                                  const int* __restrict__ partial_scan,
                                                  int* __restrict__ out, int n) {
    __shared__ int buf[256];
    int t = threadIdx.x;
    int i = blockIdx.x * 256 + t;
    int v = (i < n) ? in[i] : 0;
    buf[t] = v;
    __syncthreads();
    for (int off = 1; off < 256; off <<= 1) {
        int x = (t >= off) ? buf[t - off] : 0;
        __syncthreads();
        buf[t] += x;
        __syncthreads();
    }
    if (i < n) out[i] = partial_scan[blockIdx.x] + buf[t] - v;
}

__global__ __launch_bounds__(256) void scatter_edges(const int* __restrict__ src,
                                                     const int* __restrict__ dst,
                                                     const int* __restrict__ row_start,
                                                     int* __restrict__ deg,
                                                     int* __restrict__ csr_src, int E) {
    int e = blockIdx.x * blockDim.x + threadIdx.x;
    if (e >= E) return;
    int d = dst[e];
    int pos = atomicSub(&deg[d], 1) - 1;
    csr_src[row_start[d] + pos] = src[e];
}

// ---------------- GEMM (col4 x row blocking) + fused attn-score epilogue ----

__device__ inline void fma4(float4& a, const float4& w, float xs) {
    a.x += w.x * xs; a.y += w.y * xs; a.z += w.z * xs; a.w += w.w * xs;
}
__device__ inline float dot4(const float4& a, const float4& b) {
    return a.x * b.x + a.y * b.y + a.z * b.z + a.w * b.w;
}

template <int K, int M, int G, int RPG, int H, int D>
__global__ __launch_bounds__((M / 4) * G) void gemm_feat4(const float* __restrict__ x,
                                                          const float* __restrict__ W,
                                                          const float* __restrict__ al,
                                                          const float* __restrict__ ar,
                                                          float* __restrict__ out,
                                                          float* __restrict__ el,
                                                          float* __restrict__ er, int N) {
    constexpr int CT = M / 4;
    constexpr int LPH = D / 4;
    constexpr int ROWS = G * RPG;
    constexpr int NT = CT * G;
    static_assert(LPH == 16 && (CT % LPH) == 0, "epilogue assumes 16-lane head groups");
    __shared__ float4 sx[ROWS][K / 4];
    const int tid = threadIdx.x;
    const int col4 = tid % CT;
    const int grp = tid / CT;
    const int h = col4 / LPH;
    const float4* __restrict__ W4 = (const float4*)W;
    const float4* __restrict__ x4 = (const float4*)x;
    const float4 av = ((const float4*)al)[col4];
    const float4 rv = ((const float4*)ar)[col4];

    for (int base = blockIdx.x * ROWS; base < N; base += gridDim.x * ROWS) {
        __syncthreads();
        for (int i = tid; i < ROWS * (K / 4); i += NT) {
            int r = i / (K / 4), c = i % (K / 4);
            int row = base + r;
            sx[r][c] = (row < N) ? x4[(size_t)row * (K / 4) + c] : float4{0.f, 0.f, 0.f, 0.f};
        }
        __syncthreads();
        float4 acc[RPG];
#pragma unroll
        for (int rr = 0; rr < RPG; ++rr) acc[rr] = float4{0.f, 0.f, 0.f, 0.f};
#pragma unroll 4
        for (int k4 = 0; k4 < K / 4; ++k4) {
            float4 w0 = W4[(size_t)(4 * k4 + 0) * CT + col4];
            float4 w1 = W4[(size_t)(4 * k4 + 1) * CT + col4];
            float4 w2 = W4[(size_t)(4 * k4 + 2) * CT + col4];
            float4 w3 = W4[(size_t)(4 * k4 + 3) * CT + col4];
#pragma unroll
            for (int rr = 0; rr < RPG; ++rr) {
                float4 xv = sx[grp * RPG + rr][k4];
                fma4(acc[rr], w0, xv.x);
                fma4(acc[rr], w1, xv.y);
                fma4(acc[rr], w2, xv.z);
                fma4(acc[rr], w3, xv.w);
            }
        }
#pragma unroll
        for (int rr = 0; rr < RPG; ++rr) {
            int row = base + grp * RPG + rr;
            if (row < N) ((float4*)out)[(size_t)row * CT + col4] = acc[rr];
        }
#pragma unroll
        for (int rr = 0; rr < RPG; ++rr) {
            float pl = dot4(acc[rr], av);
            float pr = dot4(acc[rr], rv);
#pragma unroll
            for (int off = 1; off < LPH; off <<= 1) {
                pl += __shfl_xor(pl, off);
                pr += __shfl_xor(pr, off);
            }
            if ((col4 % LPH) == 0) {
                int row = base + grp * RPG + rr;
                if (row < N) {
                    el[(size_t)row * H + h] = pl;
                    er[(size_t)row * H + h] = pr;
                }
            }
        }
    }
}

// scalar-LDS gemm for M=40 (layer 2) with LDS-atomic attn epilogue (H=1)
template <int K, int M>
__global__ __launch_bounds__(256) void gemm_feat(const float* __restrict__ x,
                                                 const float* __restrict__ W,
                                                 const float* __restrict__ al,
                                                 const float* __restrict__ ar,
                                                 float* __restrict__ out,
                                                 float* __restrict__ el,
                                                 float* __restrict__ er, int N) {
    constexpr int NGRP = 256 / M;
    constexpr int RPG = 8;
    constexpr int ROWS = NGRP * RPG;
    __shared__ float sx[ROWS][K];
    __shared__ float sel[ROWS], ser[ROWS];
    const int tid = threadIdx.x;
    const int col = tid % M;
    const int grp = tid / M;
    for (int base = blockIdx.x * ROWS; base < N; base += gridDim.x * ROWS) {
        __syncthreads();
        for (int i = tid; i < ROWS * K; i += 256) {
            int r = i / K, c = i % K;
            int row = base + r;
            sx[r][c] = (row < N) ? x[(size_t)row * K + c] : 0.f;
        }
        if (tid < ROWS) { sel[tid] = 0.f; ser[tid] = 0.f; }
        __syncthreads();
        if (grp < NGRP) {
            float acc[RPG];
#pragma unroll
            for (int rr = 0; rr < RPG; ++rr) acc[rr] = 0.f;
            for (int k = 0; k < K; ++k) {
                float w = W[(size_t)k * M + col];
#pragma unroll
                for (int rr = 0; rr < RPG; ++rr) acc[rr] += sx[grp * RPG + rr][k] * w;
            }
            float alc = al[col], arc = ar[col];
#pragma unroll
            for (int rr = 0; rr < RPG; ++rr) {
                int row = base + grp * RPG + rr;
                if (row < N) out[(size_t)row * M + col] = acc[rr];
                atomicAdd(&sel[grp * RPG + rr], acc[rr] * alc);
                atomicAdd(&ser[grp * RPG + rr], acc[rr] * arc);
            }
        }
        __syncthreads();
        if (tid < ROWS) {
            int row = base + tid;
            if (row < N) { el[row] = sel[tid]; er[row] = ser[tid]; }
        }
    }
}

// ---------------- per-dst softmax + aggregation (one wave per dst) ----------------
// 16-edge batches: 4 x 16-lane groups, each group owns 4 edges; ALL row loads
// for the batch are issued before the FMA phase to maximize loads-in-flight.

template <int H, int D>
__global__ __launch_bounds__(256) void gat_aggregate(const float* __restrict__ feat,
                                                     const float* __restrict__ el,
                                                     const float* __restrict__ er,
                                                     const int* __restrict__ row_start,
                                                     const int* __restrict__ csr_src,
                                                     const float* __restrict__ bias,
                                                     float* __restrict__ out, int N) {
    constexpr int Q = D / 4;  // float4s per head row
    int dstn = (blockIdx.x * blockDim.x + threadIdx.x) >> 6;
    int lane = threadIdx.x & 63;
    if (dstn >= N) return;
    int beg = row_start[dstn], end = row_start[dstn + 1];
    int cnt = end - beg;

    float er_d[H];
#pragma unroll
    for (int h = 0; h < H; ++h) er_d[h] = er[(size_t)dstn * H + h];

    float ssum[H];
    float4 acc[H];
#pragma unroll
    for (int h = 0; h < H; ++h) { ssum[h] = 0.f; acc[h] = float4{0.f, 0.f, 0.f, 0.f}; }

    const int g = lane >> 4;    // edge-group 0..3
    const int ln = lane & 15;   // quad within row

    // batch gather helper: edges j+g, j+4+g, j+8+g, j+12+g for this group
    auto gather16 = [&](int s_reg, const float p_reg[H], int j, int limit) {
        int sj[4];
        bool val[4];
#pragma unroll
        for (int t = 0; t < 4; ++t) {
            int idx = j + 4 * t + g;
            sj[t] = __shfl(s_reg, idx);
            val[t] = idx < limit;
        }
        float4 v[4][H];
        // load phase: all loads issued back-to-back
#pragma unroll
        for (int t = 0; t < 4; ++t) {
            const float4* fp = (const float4*)(feat + (size_t)sj[t] * (H * D));
#pragma unroll
            for (int h = 0; h < H; ++h) {
                v[t][h] = float4{0.f, 0.f, 0.f, 0.f};
                if (val[t] && (Q == 16 || ln < Q)) v[t][h] = fp[h * Q + ln];
            }
        }
        // fma phase
#pragma unroll
        for (int t = 0; t < 4; ++t) {
#pragma unroll
            for (int h = 0; h < H; ++h) {
                float pj = __shfl(p_reg[h], j + 4 * t + g);
                fma4(acc[h], v[t][h], pj);
            }
        }
    };

    if (cnt <= 64) {
        // scores: one edge per lane
        int idx = beg + lane;
        bool valid = idx < end;
        int s = valid ? csr_src[idx] : csr_src[beg];
        float ev[H], m[H], p[H];
        if constexpr (H == 2) {
            float2 e2 = ((const float2*)el)[s];
            ev[0] = e2.x + er_d[0];
            ev[1] = e2.y + er_d[1];
        } else {
            ev[0] = el[s] + er_d[0];
        }
#pragma unroll
        for (int h = 0; h < H; ++h) {
            float e = ev[h];
            e = (e > 0.f) ? e : NEG_SLOPE * e;
            ev[h] = e;
            m[h] = valid ? e : -INFINITY;
        }
#pragma unroll
        for (int h = 0; h < H; ++h)
#pragma unroll
            for (int off = 32; off; off >>= 1) m[h] = fmaxf(m[h], __shfl_xor(m[h], off));
#pragma unroll
        for (int h = 0; h < H; ++h) {
            p[h] = valid ? expf(ev[h] - m[h]) : 0.f;
            ssum[h] = p[h];
        }
        for (int j = 0; j < cnt; j += 16) gather16(s, p, j, cnt);
    } else {
        // general path: pass 1 max, then chunked p + batched gather
        float m[H];
#pragma unroll
        for (int h = 0; h < H; ++h) m[h] = -INFINITY;
        for (int i = beg + lane; i < end; i += 64) {
            int s = csr_src[i];
            float ev[H];
            if constexpr (H == 2) {
                float2 e2 = ((const float2*)el)[s];
                ev[0] = e2.x + er_d[0];
                ev[1] = e2.y + er_d[1];
            } else {
                ev[0] = el[s] + er_d[0];
            }
#pragma unroll
            for (int h = 0; h < H; ++h) {
                float e = ev[h];
                e = (e > 0.f) ? e : NEG_SLOPE * e;
                m[h] = fmaxf(m[h], e);
            }
        }
#pragma unroll
        for (int h = 0; h < H; ++h)
#pragma unroll
            for (int off = 32; off; off >>= 1) m[h] = fmaxf(m[h], __shfl_xor(m[h], off));

        for (int base = beg; base < end; base += 64) {
            int idx = base + lane;
            bool valid = idx < end;
            int s = valid ? csr_src[idx] : csr_src[beg];
            float p[H];
            float ev[H];
            if constexpr (H == 2) {
                float2 e2 = ((const float2*)el)[s];
                ev[0] = e2.x + er_d[0];
                ev[1] = e2.y + er_d[1];
            } else {
                ev[0] = el[s] + er_d[0];
            }
#pragma unroll
            for (int h = 0; h < H; ++h) {
                float e = ev[h];
                e = (e > 0.f) ? e : NEG_SLOPE * e;
                p[h] = valid ? expf(e - m[h]) : 0.f;
                ssum[h] += p[h];
            }
            int ccnt = (end - base < 64) ? end - base : 64;
            for (int j = 0; j < ccnt; j += 16) gather16(s, p, j, ccnt);
        }
    }

    // epilogue: reduce ssum across wave, acc across the 4 edge-groups
#pragma unroll
    for (int h = 0; h < H; ++h) {
#pragma unroll
        for (int off = 32; off; off >>= 1) ssum[h] += __shfl_xor(ssum[h], off);
#pragma unroll
        for (int off = 16; off <= 32; off <<= 1) {
            acc[h].x += __shfl_xor(acc[h].x, off);
            acc[h].y += __shfl_xor(acc[h].y, off);
            acc[h].z += __shfl_xor(acc[h].z, off);
            acc[h].w += __shfl_xor(acc[h].w, off);
        }
    }
    if (lane < Q) {
        float4* op = (float4*)(out + (size_t)dstn * (H * D));
        const float4* bp = (const float4*)bias;
#pragma unroll
        for (int h = 0; h < H; ++h) {
            float inv = 1.f / ssum[h];
            float4 bv = bp[h * Q + lane];
            float4 o;
            o.x = acc[h].x * inv + bv.x;
            o.y = acc[h].y * inv + bv.y;
            o.z = acc[h].z * inv + bv.z;
            o.w = acc[h].w * inv + bv.w;
            op[h * Q + lane] = o;
        }
    }
}

// ---------------- launch ----------------

extern "C" void kernel_launch(void* const* d_in, const int* in_sizes, int n_in,
                              void* d_out, int out_size, void* d_ws, size_t ws_size,
                              hipStream_t stream) {
    const float* in_feat = (const float*)d_in[0];
    const int*   src     = (const int*)d_in[1];
    const int*   dst     = (const int*)d_in[2];
    const float* W0 = (const float*)d_in[3];
    const float* al0 = (const float*)d_in[4];
    const float* ar0 = (const float*)d_in[5];
    const float* b0 = (const float*)d_in[6];
    const float* W1 = (const float*)d_in[7];
    const float* al1 = (const float*)d_in[8];
    const float* ar1 = (const float*)d_in[9];
    const float* b1 = (const float*)d_in[10];
    const float* W2 = (const float*)d_in[11];
    const float* al2 = (const float*)d_in[12];
    const float* ar2 = (const float*)d_in[13];
    const float* b2 = (const float*)d_in[14];
    float* out = (float*)d_out;

    const int N = in_sizes[0] / 128;  // 50000
    const int E = in_sizes[1];        // 850000

    char* ws = (char*)d_ws;
    auto alloc = [&](size_t bytes) -> void* {
        void* p = (void*)ws;
        ws += (bytes + 255) & ~(size_t)255;
        return p;
    };
    int* deg       = (int*)alloc((size_t)N * 4);
    int* row_start = (int*)alloc((size_t)(N + 1) * 4);
    int* csr_src   = (int*)alloc((size_t)E * 4);
    int* partial      = (int*)alloc(256 * 4);
    int* partial_scan = (int*)alloc(256 * 4);
    float* feat    = (float*)alloc((size_t)N * 128 * 4);
    float* el      = (float*)alloc((size_t)N * 2 * 4);
    float* er      = (float*)alloc((size_t)N * 2 * 4);
    float* h0      = (float*)alloc((size_t)N * 128 * 4);
    float* h1      = (float*)alloc((size_t)N * 64 * 4);

    hipMemsetAsync(deg, 0, (size_t)N * 4, stream);

    int egrid = (E + 255) / 256;
    degree_hist<<<egrid, 256, 0, stream>>>(dst, deg, E);
    int nb = (N + 255) / 256;
    scan_block_sums<<<nb, 256, 0, stream>>>(deg, partial, N);
    scan_offsets<<<1, 256, 0, stream>>>(partial, partial_scan, &row_start[N], nb);
    scan_final<<<nb, 256, 0, stream>>>(deg, partial_scan, row_start, N);
    scatter_edges<<<egrid, 256, 0, stream>>>(src, dst, row_start, deg, csr_src, E);

    int ngrid = (N * 64 + 255) / 256;  // one wave per node

    // layer 0: in=128, H=2, D=64
    {
        int g = (N + 63) / 64;
        gemm_feat4<128, 128, 8, 8, 2, 64><<<g, 256, 0, stream>>>(in_feat, W0, al0, ar0, feat, el, er, N);
        gat_aggregate<2, 64><<<ngrid, 256, 0, stream>>>(feat, el, er, row_start, csr_src, b0, h0, N);
    }
    // layer 1: in=128, H=1, D=64
    {
        int g = (N + 63) / 64;
        gemm_feat4<128, 64, 16, 4, 1, 64><<<g, 256, 0, stream>>>(h0, W1, al1, ar1, feat, el, er, N);
        gat_aggregate<1, 64><<<ngrid, 256, 0, stream>>>(feat, el, er, row_start, csr_src, b1, h1, N);
    }
    // layer 2: in=64, H=1, D=40
    {
        constexpr int ROWS = (256 / 40) * 8;
        int g = (N + ROWS - 1) / ROWS;
        gemm_feat<64, 40><<<g, 256, 0, stream>>>(h1, W2, al2, ar2, feat, el, er, N);
        gat_aggregate<1, 40><<<ngrid, 256, 0, stream>>>(feat, el, er, row_start, csr_src, b2, out, N);
    }
}

// Round 6
// 381.949 us; speedup vs baseline: 1.8443x; 1.0650x over previous
//
#include <hip/hip_runtime.h>
#include <hip/hip_fp16.h>
#include <math.h>

#define NEG_SLOPE 0.2f

// ---------------- fp16 pack/unpack helpers ----------------

__device__ inline float2 up2(unsigned u) {
    __half2 h;
    __builtin_memcpy(&h, &u, 4);
    return __half22float2(h);
}
__device__ inline unsigned pk2(float a, float b) {
    __half2 h = __floats2half2_rn(a, b);
    unsigned u;
    __builtin_memcpy(&u, &h, 4);
    return u;
}
__device__ inline void fma8(float* acc, const uint4& v, float p) {
    float2 f;
    f = up2(v.x); acc[0] += f.x * p; acc[1] += f.y * p;
    f = up2(v.y); acc[2] += f.x * p; acc[3] += f.y * p;
    f = up2(v.z); acc[4] += f.x * p; acc[5] += f.y * p;
    f = up2(v.w); acc[6] += f.x * p; acc[7] += f.y * p;
}

// ---------------- CSR build ----------------

__global__ __launch_bounds__(256) void degree_hist(const int* __restrict__ dst,
                                                   int* __restrict__ deg, int E) {
    int e = blockIdx.x * blockDim.x + threadIdx.x;
    if (e < E) atomicAdd(&deg[dst[e]], 1);
}

__global__ __launch_bounds__(256) void scan_block_sums(const int* __restrict__ in,
                                                       int* __restrict__ partial, int n) {
    int i = blockIdx.x * 256 + threadIdx.x;
    int v = (i < n) ? in[i] : 0;
#pragma unroll
    for (int off = 32; off; off >>= 1) v += __shfl_xor(v, off);
    __shared__ int wsum[4];
    if ((threadIdx.x & 63) == 0) wsum[threadIdx.x >> 6] = v;
    __syncthreads();
    if (threadIdx.x == 0) partial[blockIdx.x] = wsum[0] + wsum[1] + wsum[2] + wsum[3];
}

__global__ __launch_bounds__(256) void scan_offsets(const int* __restrict__ partial,
                                                    int* __restrict__ partial_scan,
                                                    int* __restrict__ total_out, int nb) {
    __shared__ int buf[256];
    int t = threadIdx.x;
    int v = (t < nb) ? partial[t] : 0;
    buf[t] = v;
    __syncthreads();
    for (int off = 1; off < 256; off <<= 1) {
        int x = (t >= off) ? buf[t - off] : 0;
        __syncthreads();
        buf[t] += x;
        __syncthreads();
    }
    partial_scan[t] = buf[t] - v;
    if (t == 255) *total_out = buf[255];
}

__global__ __launch_bounds__(256) void scan_final(const int* __restrict__ in,
                                                  const int* __restrict__ partial_scan,
                                                  int* __restrict__ out, int n) {
    __shared__ int buf[256];
    int t = threadIdx.x;
    int i = blockIdx.x * 256 + t;
    int v = (i < n) ? in[i] : 0;
    buf[t] = v;
    __syncthreads();
    for (int off = 1; off < 256; off <<= 1) {
        int x = (t >= off) ? buf[t - off] : 0;
        __syncthreads();
        buf[t] += x;
        __syncthreads();
    }
    if (i < n) out[i] = partial_scan[blockIdx.x] + buf[t] - v;
}

__global__ __launch_bounds__(256) void scatter_edges(const int* __restrict__ src,
                                                     const int* __restrict__ dst,
                                                     const int* __restrict__ row_start,
                                                     int* __restrict__ deg,
                                                     int* __restrict__ csr_src, int E) {
    int e = blockIdx.x * blockDim.x + threadIdx.x;
    if (e >= E) return;
    int d = dst[e];
    int pos = atomicSub(&deg[d], 1) - 1;
    csr_src[row_start[d] + pos] = src[e];
}

// ---------------- GEMM (col4 x row blocking) + fused attn-score epilogue ----
// feat output is fp16; el/er computed from fp32 accumulators.

__device__ inline void fma4(float4& a, const float4& w, float xs) {
    a.x += w.x * xs; a.y += w.y * xs; a.z += w.z * xs; a.w += w.w * xs;
}
__device__ inline float dot4(const float4& a, const float4& b) {
    return a.x * b.x + a.y * b.y + a.z * b.z + a.w * b.w;
}

template <int K, int M, int G, int RPG, int H, int D>
__global__ __launch_bounds__((M / 4) * G) void gemm_feat4(const float* __restrict__ x,
                                                          const float* __restrict__ W,
                                                          const float* __restrict__ al,
                                                          const float* __restrict__ ar,
                                                          __half* __restrict__ outh,
                                                          float* __restrict__ el,
                                                          float* __restrict__ er, int N) {
    constexpr int CT = M / 4;
    constexpr int LPH = D / 4;
    constexpr int ROWS = G * RPG;
    constexpr int NT = CT * G;
    static_assert(LPH == 16 && (CT % LPH) == 0, "epilogue assumes 16-lane head groups");
    __shared__ float4 sx[ROWS][K / 4];
    const int tid = threadIdx.x;
    const int col4 = tid % CT;
    const int grp = tid / CT;
    const int h = col4 / LPH;
    const float4* __restrict__ W4 = (const float4*)W;
    const float4* __restrict__ x4 = (const float4*)x;
    const float4 av = ((const float4*)al)[col4];
    const float4 rv = ((const float4*)ar)[col4];

    for (int base = blockIdx.x * ROWS; base < N; base += gridDim.x * ROWS) {
        __syncthreads();
        for (int i = tid; i < ROWS * (K / 4); i += NT) {
            int r = i / (K / 4), c = i % (K / 4);
            int row = base + r;
            sx[r][c] = (row < N) ? x4[(size_t)row * (K / 4) + c] : float4{0.f, 0.f, 0.f, 0.f};
        }
        __syncthreads();
        float4 acc[RPG];
#pragma unroll
        for (int rr = 0; rr < RPG; ++rr) acc[rr] = float4{0.f, 0.f, 0.f, 0.f};
#pragma unroll 4
        for (int k4 = 0; k4 < K / 4; ++k4) {
            float4 w0 = W4[(size_t)(4 * k4 + 0) * CT + col4];
            float4 w1 = W4[(size_t)(4 * k4 + 1) * CT + col4];
            float4 w2 = W4[(size_t)(4 * k4 + 2) * CT + col4];
            float4 w3 = W4[(size_t)(4 * k4 + 3) * CT + col4];
#pragma unroll
            for (int rr = 0; rr < RPG; ++rr) {
                float4 xv = sx[grp * RPG + rr][k4];
                fma4(acc[rr], w0, xv.x);
                fma4(acc[rr], w1, xv.y);
                fma4(acc[rr], w2, xv.z);
                fma4(acc[rr], w3, xv.w);
            }
        }
#pragma unroll
        for (int rr = 0; rr < RPG; ++rr) {
            int row = base + grp * RPG + rr;
            if (row < N) {
                uint2 pkd;
                pkd.x = pk2(acc[rr].x, acc[rr].y);
                pkd.y = pk2(acc[rr].z, acc[rr].w);
                ((uint2*)(outh + (size_t)row * M))[col4] = pkd;
            }
        }
#pragma unroll
        for (int rr = 0; rr < RPG; ++rr) {
            float pl = dot4(acc[rr], av);
            float pr = dot4(acc[rr], rv);
#pragma unroll
            for (int off = 1; off < LPH; off <<= 1) {
                pl += __shfl_xor(pl, off);
                pr += __shfl_xor(pr, off);
            }
            if ((col4 % LPH) == 0) {
                int row = base + grp * RPG + rr;
                if (row < N) {
                    el[(size_t)row * H + h] = pl;
                    er[(size_t)row * H + h] = pr;
                }
            }
        }
    }
}

// scalar-LDS gemm for M=40 (layer 2) with LDS-atomic attn epilogue (H=1)
template <int K, int M>
__global__ __launch_bounds__(256) void gemm_feat(const float* __restrict__ x,
                                                 const float* __restrict__ W,
                                                 const float* __restrict__ al,
                                                 const float* __restrict__ ar,
                                                 __half* __restrict__ outh,
                                                 float* __restrict__ el,
                                                 float* __restrict__ er, int N) {
    constexpr int NGRP = 256 / M;
    constexpr int RPG = 8;
    constexpr int ROWS = NGRP * RPG;
    __shared__ float sx[ROWS][K];
    __shared__ float sel[ROWS], ser[ROWS];
    const int tid = threadIdx.x;
    const int col = tid % M;
    const int grp = tid / M;
    for (int base = blockIdx.x * ROWS; base < N; base += gridDim.x * ROWS) {
        __syncthreads();
        for (int i = tid; i < ROWS * K; i += 256) {
            int r = i / K, c = i % K;
            int row = base + r;
            sx[r][c] = (row < N) ? x[(size_t)row * K + c] : 0.f;
        }
        if (tid < ROWS) { sel[tid] = 0.f; ser[tid] = 0.f; }
        __syncthreads();
        if (grp < NGRP) {
            float acc[RPG];
#pragma unroll
            for (int rr = 0; rr < RPG; ++rr) acc[rr] = 0.f;
            for (int k = 0; k < K; ++k) {
                float w = W[(size_t)k * M + col];
#pragma unroll
                for (int rr = 0; rr < RPG; ++rr) acc[rr] += sx[grp * RPG + rr][k] * w;
            }
            float alc = al[col], arc = ar[col];
#pragma unroll
            for (int rr = 0; rr < RPG; ++rr) {
                int row = base + grp * RPG + rr;
                if (row < N) outh[(size_t)row * M + col] = __float2half_rn(acc[rr]);
                atomicAdd(&sel[grp * RPG + rr], acc[rr] * alc);
                atomicAdd(&ser[grp * RPG + rr], acc[rr] * arc);
            }
        }
        __syncthreads();
        if (tid < ROWS) {
            int row = base + tid;
            if (row < N) { el[row] = sel[tid]; er[row] = ser[tid]; }
        }
    }
}

// ---------------- per-dst softmax + aggregation (one wave per dst) ----------------
// fp16 feat rows: a 16-lane group reads a full edge row as uint4 (8 halves/lane).
// 4 edges per group per j-step, all loads issued before the FMA phase.
// No validity predication: tail slots load a cache-hot safe row with p=0.

template <int H, int D>
__global__ __launch_bounds__(256) void gat_aggregate(const __half* __restrict__ feat,
                                                     const float* __restrict__ el,
                                                     const float* __restrict__ er,
                                                     const int* __restrict__ row_start,
                                                     const int* __restrict__ csr_src,
                                                     const float* __restrict__ bias,
                                                     float* __restrict__ out, int N) {
    constexpr int NL = (H * D) / 8;  // lanes carrying row data (16, 8, or 5)
    int dstn = (blockIdx.x * blockDim.x + threadIdx.x) >> 6;
    int lane = threadIdx.x & 63;
    if (dstn >= N) return;
    int beg = row_start[dstn], end = row_start[dstn + 1];
    int cnt = end - beg;

    float er_d[H];
#pragma unroll
    for (int h = 0; h < H; ++h) er_d[h] = er[(size_t)dstn * H + h];

    float ssum[H];
    float acc8[8];
#pragma unroll
    for (int h = 0; h < H; ++h) ssum[h] = 0.f;
#pragma unroll
    for (int i = 0; i < 8; ++i) acc8[i] = 0.f;

    const int g = lane >> 4;   // edge-group 0..3
    const int ln = lane & 15;  // 8-half segment within row

    auto gather = [&](int s_reg, const float p_reg[H], int j) {
        uint4 v[4];
#pragma unroll
        for (int t = 0; t < 4; ++t) {
            int sj = __shfl(s_reg, j + 4 * t + g);
            const uint4* fp = (const uint4*)(feat + (size_t)sj * (H * D));
            v[t] = (NL == 16 || ln < NL) ? fp[ln] : uint4{0, 0, 0, 0};
        }
#pragma unroll
        for (int t = 0; t < 4; ++t) {
            int e = j + 4 * t + g;
            float pj0 = __shfl(p_reg[0], e);
            float pj;
            if constexpr (H == 2) {
                float pj1 = __shfl(p_reg[1], e);
                pj = (ln >= 8) ? pj1 : pj0;
            } else {
                pj = pj0;
            }
            fma8(acc8, v[t], pj);
        }
    };

    if (cnt <= 64) {
        int idx = beg + lane;
        bool valid = idx < end;
        int s = valid ? csr_src[idx] : csr_src[beg];
        float ev[H], m[H], p[H];
        if constexpr (H == 2) {
            float2 e2 = ((const float2*)el)[s];
            ev[0] = e2.x + er_d[0];
            ev[1] = e2.y + er_d[1];
        } else {
            ev[0] = el[s] + er_d[0];
        }
#pragma unroll
        for (int h = 0; h < H; ++h) {
            float e = ev[h];
            e = (e > 0.f) ? e : NEG_SLOPE * e;
            ev[h] = e;
            m[h] = valid ? e : -INFINITY;
        }
#pragma unroll
        for (int h = 0; h < H; ++h)
#pragma unroll
            for (int off = 32; off; off >>= 1) m[h] = fmaxf(m[h], __shfl_xor(m[h], off));
#pragma unroll
        for (int h = 0; h < H; ++h) {
            p[h] = valid ? expf(ev[h] - m[h]) : 0.f;
            ssum[h] = p[h];
        }
        for (int j = 0; j < cnt; j += 16) gather(s, p, j);
    } else {
        float m[H];
#pragma unroll
        for (int h = 0; h < H; ++h) m[h] = -INFINITY;
        for (int i = beg + lane; i < end; i += 64) {
            int s = csr_src[i];
            float ev[H];
            if constexpr (H == 2) {
                float2 e2 = ((const float2*)el)[s];
                ev[0] = e2.x + er_d[0];
                ev[1] = e2.y + er_d[1];
            } else {
                ev[0] = el[s] + er_d[0];
            }
#pragma unroll
            for (int h = 0; h < H; ++h) {
                float e = ev[h];
                e = (e > 0.f) ? e : NEG_SLOPE * e;
                m[h] = fmaxf(m[h], e);
            }
        }
#pragma unroll
        for (int h = 0; h < H; ++h)
#pragma unroll
            for (int off = 32; off; off >>= 1) m[h] = fmaxf(m[h], __shfl_xor(m[h], off));

        for (int base = beg; base < end; base += 64) {
            int idx = base + lane;
            bool valid = idx < end;
            int s = valid ? csr_src[idx] : csr_src[beg];
            float p[H];
            float ev[H];
            if constexpr (H == 2) {
                float2 e2 = ((const float2*)el)[s];
                ev[0] = e2.x + er_d[0];
                ev[1] = e2.y + er_d[1];
            } else {
                ev[0] = el[s] + er_d[0];
            }
#pragma unroll
            for (int h = 0; h < H; ++h) {
                float e = ev[h];
                e = (e > 0.f) ? e : NEG_SLOPE * e;
                p[h] = valid ? expf(e - m[h]) : 0.f;
                ssum[h] += p[h];
            }
            int ccnt = (end - base < 64) ? end - base : 64;
            for (int j = 0; j < ccnt; j += 16) gather(s, p, j);
        }
    }

    // reduce ssum across wave; acc8 across the 4 edge-groups
#pragma unroll
    for (int h = 0; h < H; ++h)
#pragma unroll
        for (int off = 32; off; off >>= 1) ssum[h] += __shfl_xor(ssum[h], off);
#pragma unroll
    for (int i = 0; i < 8; ++i) {
        acc8[i] += __shfl_xor(acc8[i], 16);
        acc8[i] += __shfl_xor(acc8[i], 32);
    }
    if (lane < NL) {
        float inv;
        if constexpr (H == 2) inv = 1.f / ((lane >= 8) ? ssum[1] : ssum[0]);
        else inv = 1.f / ssum[0];
        float4* op = (float4*)(out + (size_t)dstn * (H * D));
        const float4* bp = (const float4*)bias;
        float4 bv0 = bp[2 * lane], bv1 = bp[2 * lane + 1];
        float4 o0, o1;
        o0.x = acc8[0] * inv + bv0.x; o0.y = acc8[1] * inv + bv0.y;
        o0.z = acc8[2] * inv + bv0.z; o0.w = acc8[3] * inv + bv0.w;
        o1.x = acc8[4] * inv + bv1.x; o1.y = acc8[5] * inv + bv1.y;
        o1.z = acc8[6] * inv + bv1.z; o1.w = acc8[7] * inv + bv1.w;
        op[2 * lane] = o0;
        op[2 * lane + 1] = o1;
    }
}

// ---------------- launch ----------------

extern "C" void kernel_launch(void* const* d_in, const int* in_sizes, int n_in,
                              void* d_out, int out_size, void* d_ws, size_t ws_size,
                              hipStream_t stream) {
    const float* in_feat = (const float*)d_in[0];
    const int*   src     = (const int*)d_in[1];
    const int*   dst     = (const int*)d_in[2];
    const float* W0 = (const float*)d_in[3];
    const float* al0 = (const float*)d_in[4];
    const float* ar0 = (const float*)d_in[5];
    const float* b0 = (const float*)d_in[6];
    const float* W1 = (const float*)d_in[7];
    const float* al1 = (const float*)d_in[8];
    const float* ar1 = (const float*)d_in[9];
    const float* b1 = (const float*)d_in[10];
    const float* W2 = (const float*)d_in[11];
    const float* al2 = (const float*)d_in[12];
    const float* ar2 = (const float*)d_in[13];
    const float* b2 = (const float*)d_in[14];
    float* out = (float*)d_out;

    const int N = in_sizes[0] / 128;  // 50000
    const int E = in_sizes[1];        // 850000

    char* ws = (char*)d_ws;
    auto alloc = [&](size_t bytes) -> void* {
        void* p = (void*)ws;
        ws += (bytes + 255) & ~(size_t)255;
        return p;
    };
    int* deg       = (int*)alloc((size_t)N * 4);
    int* row_start = (int*)alloc((size_t)(N + 1) * 4);
    int* csr_src   = (int*)alloc((size_t)E * 4);
    int* partial      = (int*)alloc(256 * 4);
    int* partial_scan = (int*)alloc(256 * 4);
    __half* feat   = (__half*)alloc((size_t)N * 128 * 2);
    float* el      = (float*)alloc((size_t)N * 2 * 4);
    float* er      = (float*)alloc((size_t)N * 2 * 4);
    float* h0      = (float*)alloc((size_t)N * 128 * 4);
    float* h1      = (float*)alloc((size_t)N * 64 * 4);

    hipMemsetAsync(deg, 0, (size_t)N * 4, stream);

    int egrid = (E + 255) / 256;
    degree_hist<<<egrid, 256, 0, stream>>>(dst, deg, E);
    int nb = (N + 255) / 256;
    scan_block_sums<<<nb, 256, 0, stream>>>(deg, partial, N);
    scan_offsets<<<1, 256, 0, stream>>>(partial, partial_scan, &row_start[N], nb);
    scan_final<<<nb, 256, 0, stream>>>(deg, partial_scan, row_start, N);
    scatter_edges<<<egrid, 256, 0, stream>>>(src, dst, row_start, deg, csr_src, E);

    int ngrid = (N * 64 + 255) / 256;  // one wave per node

    // layer 0: in=128, H=2, D=64
    {
        int g = (N + 63) / 64;
        gemm_feat4<128, 128, 8, 8, 2, 64><<<g, 256, 0, stream>>>(in_feat, W0, al0, ar0, feat, el, er, N);
        gat_aggregate<2, 64><<<ngrid, 256, 0, stream>>>(feat, el, er, row_start, csr_src, b0, h0, N);
    }
    // layer 1: in=128, H=1, D=64
    {
        int g = (N + 63) / 64;
        gemm_feat4<128, 64, 16, 4, 1, 64><<<g, 256, 0, stream>>>(h0, W1, al1, ar1, feat, el, er, N);
        gat_aggregate<1, 64><<<ngrid, 256, 0, stream>>>(feat, el, er, row_start, csr_src, b1, h1, N);
    }
    // layer 2: in=64, H=1, D=40
    {
        constexpr int ROWS = (256 / 40) * 8;
        int g = (N + ROWS - 1) / ROWS;
        gemm_feat<64, 40><<<g, 256, 0, stream>>>(h1, W2, al2, ar2, feat, el, er, N);
        gat_aggregate<1, 40><<<ngrid, 256, 0, stream>>>(feat, el, er, row_start, csr_src, b2, out, N);
    }
}

// Round 7
// 348.285 us; speedup vs baseline: 2.0226x; 1.0967x over previous
//
#include <hip/hip_runtime.h>
#include <hip/hip_fp16.h>
#include <math.h>

#define NEG_SLOPE 0.2f

// ---------------- fp16 pack/unpack helpers ----------------

__device__ inline float2 up2(unsigned u) {
    __half2 h;
    __builtin_memcpy(&h, &u, 4);
    return __half22float2(h);
}
__device__ inline unsigned pk2(float a, float b) {
    __half2 h = __floats2half2_rn(a, b);
    unsigned u;
    __builtin_memcpy(&u, &h, 4);
    return u;
}
__device__ inline void fma8(float* acc, const uint4& v, float p) {
    float2 f;
    f = up2(v.x); acc[0] += f.x * p; acc[1] += f.y * p;
    f = up2(v.y); acc[2] += f.x * p; acc[3] += f.y * p;
    f = up2(v.z); acc[4] += f.x * p; acc[5] += f.y * p;
    f = up2(v.w); acc[6] += f.x * p; acc[7] += f.y * p;
}
__device__ inline void fma4(float4& a, const float4& w, float xs) {
    a.x += w.x * xs; a.y += w.y * xs; a.z += w.z * xs; a.w += w.w * xs;
}
__device__ inline float dot4(const float4& a, const float4& b) {
    return a.x * b.x + a.y * b.y + a.z * b.z + a.w * b.w;
}

// ---------------- CSR build ----------------

__global__ __launch_bounds__(256) void degree_hist(const int* __restrict__ dst,
                                                   int* __restrict__ deg, int E) {
    int e = blockIdx.x * blockDim.x + threadIdx.x;
    if (e < E) atomicAdd(&deg[dst[e]], 1);
}

__global__ __launch_bounds__(256) void scan_block_sums(const int* __restrict__ in,
                                                       int* __restrict__ partial, int n) {
    int i = blockIdx.x * 256 + threadIdx.x;
    int v = (i < n) ? in[i] : 0;
#pragma unroll
    for (int off = 32; off; off >>= 1) v += __shfl_xor(v, off);
    __shared__ int wsum[4];
    if ((threadIdx.x & 63) == 0) wsum[threadIdx.x >> 6] = v;
    __syncthreads();
    if (threadIdx.x == 0) partial[blockIdx.x] = wsum[0] + wsum[1] + wsum[2] + wsum[3];
}

__global__ __launch_bounds__(256) void scan_offsets(const int* __restrict__ partial,
                                                    int* __restrict__ partial_scan,
                                                    int* __restrict__ total_out, int nb) {
    __shared__ int buf[256];
    int t = threadIdx.x;
    int v = (t < nb) ? partial[t] : 0;
    buf[t] = v;
    __syncthreads();
    for (int off = 1; off < 256; off <<= 1) {
        int x = (t >= off) ? buf[t - off] : 0;
        __syncthreads();
        buf[t] += x;
        __syncthreads();
    }
    partial_scan[t] = buf[t] - v;
    if (t == 255) *total_out = buf[255];
}

__global__ __launch_bounds__(256) void scan_final(const int* __restrict__ in,
                                                  const int* __restrict__ partial_scan,
                                                  int* __restrict__ out, int n) {
    __shared__ int buf[256];
    int t = threadIdx.x;
    int i = blockIdx.x * 256 + t;
    int v = (i < n) ? in[i] : 0;
    buf[t] = v;
    __syncthreads();
    for (int off = 1; off < 256; off <<= 1) {
        int x = (t >= off) ? buf[t - off] : 0;
        __syncthreads();
        buf[t] += x;
        __syncthreads();
    }
    if (i < n) out[i] = partial_scan[blockIdx.x] + buf[t] - v;
}

__global__ __launch_bounds__(256) void scatter_edges(const int* __restrict__ src,
                                                     const int* __restrict__ dst,
                                                     const int* __restrict__ row_start,
                                                     int* __restrict__ deg,
                                                     int* __restrict__ csr_src, int E) {
    int e = blockIdx.x * blockDim.x + threadIdx.x;
    if (e >= E) return;
    int d = dst[e];
    int pos = atomicSub(&deg[d], 1) - 1;
    csr_src[row_start[d] + pos] = src[e];
}

// ---------------- layer-2 padding: W2 [64][40] -> [64][64], al/ar 40 -> 64 ----

__global__ __launch_bounds__(256) void pad_layer2(const float* __restrict__ W2,
                                                  const float* __restrict__ al2,
                                                  const float* __restrict__ ar2,
                                                  float* __restrict__ W2p,
                                                  float* __restrict__ al2p,
                                                  float* __restrict__ ar2p) {
    int i = blockIdx.x * 256 + threadIdx.x;
    if (i < 64 * 64) {
        int r = i >> 6, c = i & 63;
        W2p[i] = (c < 40) ? W2[r * 40 + c] : 0.f;
    }
    if (i < 64) {
        al2p[i] = (i < 40) ? al2[i] : 0.f;
        ar2p[i] = (i < 40) ? ar2[i] : 0.f;
    }
}

// ---------------- chunked-LDS GEMM + fused attn-score epilogue ----------------
// out[N,M] = x[N,K] @ W[K,M]; W chunk AND x tile staged in LDS (no global loads
// in the inner loop). feat written fp16 at row stride FSTRIDE; el/er from fp32 acc.

template <int K, int M, int G, int RPG, int H, int FSTRIDE>
__global__ __launch_bounds__((M / 4) * G) void gemm_feat_lds(const float* __restrict__ x,
                                                             const float* __restrict__ W,
                                                             const float* __restrict__ al,
                                                             const float* __restrict__ ar,
                                                             __half* __restrict__ outh,
                                                             float* __restrict__ el,
                                                             float* __restrict__ er, int N) {
    constexpr int CT = M / 4;       // col-groups (16 or 32)
    constexpr int NT = CT * G;      // threads (256)
    constexpr int ROWS = G * RPG;   // rows per block
    constexpr int KC = 32;          // k-chunk
    constexpr int KC4 = KC / 4;     // 8
    constexpr int NCH = K / KC;
    constexpr int LPH = 16;         // lanes per head group (D=64 assumed)
    static_assert(CT % LPH == 0, "CT must be a multiple of 16");
    __shared__ float4 sx[ROWS][KC4 + 1];  // +1 pad breaks 4-way bank conflicts
    __shared__ float4 sw[KC][CT];
    const int tid = threadIdx.x;
    const int col4 = tid % CT;
    const int grp = tid / CT;
    const int h = col4 / LPH;
    const float4* __restrict__ W4 = (const float4*)W;
    const float4* __restrict__ x4 = (const float4*)x;
    const float4 av = ((const float4*)al)[col4];
    const float4 rv = ((const float4*)ar)[col4];

    for (int base = blockIdx.x * ROWS; base < N; base += gridDim.x * ROWS) {
        float4 acc[RPG];
#pragma unroll
        for (int rr = 0; rr < RPG; ++rr) acc[rr] = float4{0.f, 0.f, 0.f, 0.f};

        for (int ch = 0; ch < NCH; ++ch) {
            __syncthreads();
            // stage W chunk (fully coalesced: linear in global)
#pragma unroll
            for (int i = tid; i < KC * CT; i += NT)
                sw[i / CT][i % CT] = W4[(size_t)(ch * KC) * CT + i];
            // stage x chunk
#pragma unroll
            for (int i = tid; i < ROWS * KC4; i += NT) {
                int r = i / KC4, c = i % KC4;
                int row = base + r;
                sx[r][c] = (row < N) ? x4[(size_t)row * (K / 4) + ch * KC4 + c]
                                     : float4{0.f, 0.f, 0.f, 0.f};
            }
            __syncthreads();
#pragma unroll
            for (int k4 = 0; k4 < KC4; ++k4) {
                float4 w0 = sw[4 * k4 + 0][col4];
                float4 w1 = sw[4 * k4 + 1][col4];
                float4 w2 = sw[4 * k4 + 2][col4];
                float4 w3 = sw[4 * k4 + 3][col4];
#pragma unroll
                for (int rr = 0; rr < RPG; ++rr) {
                    float4 xv = sx[grp * RPG + rr][k4];
                    fma4(acc[rr], w0, xv.x);
                    fma4(acc[rr], w1, xv.y);
                    fma4(acc[rr], w2, xv.z);
                    fma4(acc[rr], w3, xv.w);
                }
            }
        }
        // epilogue: fp16 feat write
#pragma unroll
        for (int rr = 0; rr < RPG; ++rr) {
            int row = base + grp * RPG + rr;
            if (row < N) {
                uint2 pkd;
                pkd.x = pk2(acc[rr].x, acc[rr].y);
                pkd.y = pk2(acc[rr].z, acc[rr].w);
                ((uint2*)(outh + (size_t)row * FSTRIDE))[col4] = pkd;
            }
        }
        // fused attn scores
#pragma unroll
        for (int rr = 0; rr < RPG; ++rr) {
            float pl = dot4(acc[rr], av);
            float pr = dot4(acc[rr], rv);
#pragma unroll
            for (int off = 1; off < LPH; off <<= 1) {
                pl += __shfl_xor(pl, off);
                pr += __shfl_xor(pr, off);
            }
            if ((col4 % LPH) == 0) {
                int row = base + grp * RPG + rr;
                if (row < N) {
                    el[(size_t)row * H + h] = pl;
                    er[(size_t)row * H + h] = pr;
                }
            }
        }
    }
}

// ---------------- per-dst softmax + aggregation (one wave per dst) ----------------
// fp16 feat rows at stride FSTRIDE halves; 16-lane group reads a row as uint4.
// 4 edges per group per j-step, all loads issued before the FMA phase.

template <int H, int D, int FSTRIDE>
__global__ __launch_bounds__(256) void gat_aggregate(const __half* __restrict__ feat,
                                                     const float* __restrict__ el,
                                                     const float* __restrict__ er,
                                                     const int* __restrict__ row_start,
                                                     const int* __restrict__ csr_src,
                                                     const float* __restrict__ bias,
                                                     float* __restrict__ out, int N) {
    constexpr int NL = (H * D) / 8;  // lanes carrying row data (16, 8, or 5)
    int dstn = (blockIdx.x * blockDim.x + threadIdx.x) >> 6;
    int lane = threadIdx.x & 63;
    if (dstn >= N) return;
    int beg = row_start[dstn], end = row_start[dstn + 1];
    int cnt = end - beg;

    float er_d[H];
#pragma unroll
    for (int h = 0; h < H; ++h) er_d[h] = er[(size_t)dstn * H + h];

    float ssum[H];
    float acc8[8];
#pragma unroll
    for (int h = 0; h < H; ++h) ssum[h] = 0.f;
#pragma unroll
    for (int i = 0; i < 8; ++i) acc8[i] = 0.f;

    const int g = lane >> 4;   // edge-group 0..3
    const int ln = lane & 15;  // 8-half segment within row

    auto gather = [&](int s_reg, const float p_reg[H], int j) {
        uint4 v[4];
#pragma unroll
        for (int t = 0; t < 4; ++t) {
            int sj = __shfl(s_reg, j + 4 * t + g);
            const uint4* fp = (const uint4*)(feat + (size_t)sj * FSTRIDE);
            v[t] = (NL == 16 || ln < NL) ? fp[ln] : uint4{0, 0, 0, 0};
        }
#pragma unroll
        for (int t = 0; t < 4; ++t) {
            int e = j + 4 * t + g;
            float pj0 = __shfl(p_reg[0], e);
            float pj;
            if constexpr (H == 2) {
                float pj1 = __shfl(p_reg[1], e);
                pj = (ln >= 8) ? pj1 : pj0;
            } else {
                pj = pj0;
            }
            fma8(acc8, v[t], pj);
        }
    };

    if (cnt <= 64) {
        int idx = beg + lane;
        bool valid = idx < end;
        int s = valid ? csr_src[idx] : csr_src[beg];
        float ev[H], m[H], p[H];
        if constexpr (H == 2) {
            float2 e2 = ((const float2*)el)[s];
            ev[0] = e2.x + er_d[0];
            ev[1] = e2.y + er_d[1];
        } else {
            ev[0] = el[s] + er_d[0];
        }
#pragma unroll
        for (int h = 0; h < H; ++h) {
            float e = ev[h];
            e = (e > 0.f) ? e : NEG_SLOPE * e;
            ev[h] = e;
            m[h] = valid ? e : -INFINITY;
        }
#pragma unroll
        for (int h = 0; h < H; ++h)
#pragma unroll
            for (int off = 32; off; off >>= 1) m[h] = fmaxf(m[h], __shfl_xor(m[h], off));
#pragma unroll
        for (int h = 0; h < H; ++h) {
            p[h] = valid ? expf(ev[h] - m[h]) : 0.f;
            ssum[h] = p[h];
        }
        for (int j = 0; j < cnt; j += 16) gather(s, p, j);
    } else {
        float m[H];
#pragma unroll
        for (int h = 0; h < H; ++h) m[h] = -INFINITY;
        for (int i = beg + lane; i < end; i += 64) {
            int s = csr_src[i];
            float ev[H];
            if constexpr (H == 2) {
                float2 e2 = ((const float2*)el)[s];
                ev[0] = e2.x + er_d[0];
                ev[1] = e2.y + er_d[1];
            } else {
                ev[0] = el[s] + er_d[0];
            }
#pragma unroll
            for (int h = 0; h < H; ++h) {
                float e = ev[h];
                e = (e > 0.f) ? e : NEG_SLOPE * e;
                m[h] = fmaxf(m[h], e);
            }
        }
#pragma unroll
        for (int h = 0; h < H; ++h)
#pragma unroll
            for (int off = 32; off; off >>= 1) m[h] = fmaxf(m[h], __shfl_xor(m[h], off));

        for (int base = beg; base < end; base += 64) {
            int idx = base + lane;
            bool valid = idx < end;
            int s = valid ? csr_src[idx] : csr_src[beg];
            float p[H];
            float ev[H];
            if constexpr (H == 2) {
                float2 e2 = ((const float2*)el)[s];
                ev[0] = e2.x + er_d[0];
                ev[1] = e2.y + er_d[1];
            } else {
                ev[0] = el[s] + er_d[0];
            }
#pragma unroll
            for (int h = 0; h < H; ++h) {
                float e = ev[h];
                e = (e > 0.f) ? e : NEG_SLOPE * e;
                p[h] = valid ? expf(e - m[h]) : 0.f;
                ssum[h] += p[h];
            }
            int ccnt = (end - base < 64) ? end - base : 64;
            for (int j = 0; j < ccnt; j += 16) gather(s, p, j);
        }
    }

#pragma unroll
    for (int h = 0; h < H; ++h)
#pragma unroll
        for (int off = 32; off; off >>= 1) ssum[h] += __shfl_xor(ssum[h], off);
#pragma unroll
    for (int i = 0; i < 8; ++i) {
        acc8[i] += __shfl_xor(acc8[i], 16);
        acc8[i] += __shfl_xor(acc8[i], 32);
    }
    if (lane < NL) {
        float inv;
        if constexpr (H == 2) inv = 1.f / ((lane >= 8) ? ssum[1] : ssum[0]);
        else inv = 1.f / ssum[0];
        float4* op = (float4*)(out + (size_t)dstn * (H * D));
        const float4* bp = (const float4*)bias;
        float4 bv0 = bp[2 * lane], bv1 = bp[2 * lane + 1];
        float4 o0, o1;
        o0.x = acc8[0] * inv + bv0.x; o0.y = acc8[1] * inv + bv0.y;
        o0.z = acc8[2] * inv + bv0.z; o0.w = acc8[3] * inv + bv0.w;
        o1.x = acc8[4] * inv + bv1.x; o1.y = acc8[5] * inv + bv1.y;
        o1.z = acc8[6] * inv + bv1.z; o1.w = acc8[7] * inv + bv1.w;
        op[2 * lane] = o0;
        op[2 * lane + 1] = o1;
    }
}

// ---------------- launch ----------------

extern "C" void kernel_launch(void* const* d_in, const int* in_sizes, int n_in,
                              void* d_out, int out_size, void* d_ws, size_t ws_size,
                              hipStream_t stream) {
    const float* in_feat = (const float*)d_in[0];
    const int*   src     = (const int*)d_in[1];
    const int*   dst     = (const int*)d_in[2];
    const float* W0 = (const float*)d_in[3];
    const float* al0 = (const float*)d_in[4];
    const float* ar0 = (const float*)d_in[5];
    const float* b0 = (const float*)d_in[6];
    const float* W1 = (const float*)d_in[7];
    const float* al1 = (const float*)d_in[8];
    const float* ar1 = (const float*)d_in[9];
    const float* b1 = (const float*)d_in[10];
    const float* W2 = (const float*)d_in[11];
    const float* al2 = (const float*)d_in[12];
    const float* ar2 = (const float*)d_in[13];
    const float* b2 = (const float*)d_in[14];
    float* out = (float*)d_out;

    const int N = in_sizes[0] / 128;  // 50000
    const int E = in_sizes[1];        // 850000

    char* ws = (char*)d_ws;
    auto alloc = [&](size_t bytes) -> void* {
        void* p = (void*)ws;
        ws += (bytes + 255) & ~(size_t)255;
        return p;
    };
    int* deg       = (int*)alloc((size_t)N * 4);
    int* row_start = (int*)alloc((size_t)(N + 1) * 4);
    int* csr_src   = (int*)alloc((size_t)E * 4);
    int* partial      = (int*)alloc(256 * 4);
    int* partial_scan = (int*)alloc(256 * 4);
    __half* feat   = (__half*)alloc((size_t)N * 128 * 2);
    float* el      = (float*)alloc((size_t)N * 2 * 4);
    float* er      = (float*)alloc((size_t)N * 2 * 4);
    float* h0      = (float*)alloc((size_t)N * 128 * 4);
    float* h1      = (float*)alloc((size_t)N * 64 * 4);
    float* W2p     = (float*)alloc((size_t)64 * 64 * 4);
    float* al2p    = (float*)alloc(64 * 4);
    float* ar2p    = (float*)alloc(64 * 4);

    hipMemsetAsync(deg, 0, (size_t)N * 4, stream);

    int egrid = (E + 255) / 256;
    degree_hist<<<egrid, 256, 0, stream>>>(dst, deg, E);
    int nb = (N + 255) / 256;
    scan_block_sums<<<nb, 256, 0, stream>>>(deg, partial, N);
    scan_offsets<<<1, 256, 0, stream>>>(partial, partial_scan, &row_start[N], nb);
    scan_final<<<nb, 256, 0, stream>>>(deg, partial_scan, row_start, N);
    scatter_edges<<<egrid, 256, 0, stream>>>(src, dst, row_start, deg, csr_src, E);
    pad_layer2<<<16, 256, 0, stream>>>(W2, al2, ar2, W2p, al2p, ar2p);

    int ngrid = (N * 64 + 255) / 256;  // one wave per node
    int ggrid = (N + 63) / 64;         // 64 rows per gemm block

    // layer 0: in=128, H=2, D=64
    gemm_feat_lds<128, 128, 8, 8, 2, 128><<<ggrid, 256, 0, stream>>>(in_feat, W0, al0, ar0, feat, el, er, N);
    gat_aggregate<2, 64, 128><<<ngrid, 256, 0, stream>>>(feat, el, er, row_start, csr_src, b0, h0, N);

    // layer 1: in=128, H=1, D=64
    gemm_feat_lds<128, 64, 16, 4, 1, 64><<<ggrid, 256, 0, stream>>>(h0, W1, al1, ar1, feat, el, er, N);
    gat_aggregate<1, 64, 64><<<ngrid, 256, 0, stream>>>(feat, el, er, row_start, csr_src, b1, h1, N);

    // layer 2: in=64, H=1, D=40 (padded to M=64 in W2p/al2p/ar2p)
    gemm_feat_lds<64, 64, 16, 4, 1, 64><<<ggrid, 256, 0, stream>>>(h1, W2p, al2p, ar2p, feat, el, er, N);
    gat_aggregate<1, 40, 64><<<ngrid, 256, 0, stream>>>(feat, el, er, row_start, csr_src, b2, out, N);
}